// Round 9
// baseline (403.420 us; speedup 1.0000x reference)
//
#include <hip/hip_runtime.h>
#include <hip/hip_bf16.h>

// ---------------------------------------------------------------------------
// QLenet forward, exact-math strategy:
//   All fq() outputs are e5m2 grid values (<=3 significant bits). Products of
//   two grid values have <=6-bit mantissas; dot sums (<=400 terms, bounded
//   exponent span) are EXACT in f64 -> order-independent -> matches float64
//   numpy reference. Intermediates stored as bf16 (exact for grid values);
//   LDS tiles hold f32/f64 (exact), accumulation stays f64.
// Round 19 -> 20:
//   * r19: 8-wave blocks worked (MfmaUtil 29.5->41%, kconv2 120us, total
//     395us best). kconv1 and kconv2 now tied at 120us each.
//   * kconv2 VALUBusy 30%: patch_off (2 magic-divs ~20 ops) + clamp + cvt
//     recomputed per tile although tile-invariant. Fix: soff[152] LDS table
//     (r13 style; pad k>=150 -> offset 0, weight exactly 0 -> no clamp).
//     ~6 VALU/MFMA-pair vs ~30. Weights stay f32 (LDS-BW budget: x+w ~1KB/
//     pair/wave x 8 waves ~ 75% of achieved LDS BW; f64 would oversubscribe).
//   * kconv1 VALUBusy 55%: 66 f32->f64 cvts per task (xv[11] x 6 rows) ->
//     sxf staged as f64, cvt once per element (reused ~14x).
// ---------------------------------------------------------------------------

#define BATCH 8192

typedef double d4 __attribute__((ext_vector_type(4)));

// fq on f64: round to FP(e5m2) nearest-even, subnormal granule 2^-16,
// clip +-57344. Integer RNE on the mantissa; carry propagates into exponent.
__device__ __forceinline__ double fq_d(double x) {
    long long b = __double_as_longlong(x);
    long long ab = b & 0x7fffffffffffffffLL;
    if (ab == 0) return x;                       // +-0 preserved
    double q;
    if (ab >= 0x3F10000000000000LL) {            // |x| >= 2^-14
        long long r = b + 0x0001FFFFFFFFFFFFLL + ((b >> 50) & 1LL);
        r &= 0xFFFC000000000000LL;
        q = __longlong_as_double(r);
        q = fmin(fmax(q, -57344.0), 57344.0);
    } else {                                     // subnormal grid: 2^-16
        q = rint(x * 65536.0) * 1.52587890625e-05;
    }
    return q;
}

// fq on f32 input values (exact f32 -> same e5m2 result as the f64 path).
__device__ __forceinline__ float fq_f(float x) {
    int b = __float_as_int(x);
    int ab = b & 0x7fffffff;
    if (ab == 0) return x;
    float q;
    if (ab >= 0x38800000) {                      // |x| >= 2^-14
        int r = b + 0x000FFFFF + ((b >> 21) & 1);
        r &= 0xFFE00000;                         // sign+exp+2 mantissa bits
        q = __int_as_float(r);
        q = fminf(fmaxf(q, -57344.0f), 57344.0f);
    } else {
        q = rintf(x * 65536.0f) * 1.52587890625e-05f;
    }
    return q;
}

__device__ __forceinline__ unsigned short bfbits(double q) {
    __hip_bfloat16 h = __float2bfloat16((float)q);   // exact for grid values
    return *(unsigned short*)&h;
}

__device__ __forceinline__ float bfval(unsigned short u) {
    return __bfloat162float(*(__hip_bfloat16*)&u);
}

// ---------------- merged prep (all f32-path fq) ----------------
// qw2t: conv2 weights pre-transposed to [152][16] f32 (k-major, zero-padded)
// so kconv2's LDS staging is a pure coalesced copy.
__global__ void kprep(const float* __restrict__ w1, const float* __restrict__ w2,
                      const float* __restrict__ fb1, const float* __restrict__ fb2,
                      const float* __restrict__ fb3, const float* __restrict__ fw1,
                      const float* __restrict__ fw2, const float* __restrict__ fw3,
                      float* __restrict__ qw1, float* __restrict__ qw2t,
                      float* __restrict__ qfb1, float* __restrict__ qfb2,
                      float* __restrict__ qfb3, float* __restrict__ Wt1,
                      float* __restrict__ Wt2, float* __restrict__ Wt3) {
    int i = blockIdx.x * 256 + threadIdx.x;
    if (i < 150) { qw1[i] = fq_f(w1[i]); return; }
    i -= 150;
    if (i < 2432) { int k = i >> 4, co = i & 15;
        qw2t[i] = (k < 150) ? fq_f(w2[co * 150 + k]) : 0.0f; return; }
    i -= 2432;
    if (i < 120) { qfb1[i] = fq_f(fb1[i]); return; }
    i -= 120;
    if (i < 84) { qfb2[i] = fq_f(fb2[i]); return; }
    i -= 84;
    if (i < 10) { qfb3[i] = fq_f(fb3[i]); return; }
    i -= 10;
    if (i < 51200) { int k = i / 128, o = i % 128;
        Wt1[i] = (o < 120) ? fq_f(fw1[o * 400 + k]) : 0.0f; return; }
    i -= 51200;
    if (i < 15360) { int k = i / 128, o = i % 128;
        Wt2[i] = (o < 84) ? fq_f(fw2[o * 120 + k]) : 0.0f; return; }
    i -= 15360;
    if (i < 1344) { int k = i / 16, o = i % 16;
        Wt3[i] = (o < 10) ? fq_f(fw3[o * 84 + k]) : 0.0f; return; }
}
#define PREP_TOTAL (150 + 2432 + 120 + 84 + 10 + 51200 + 15360 + 1344)

// ---------------- conv1 + fq + fused BN stats ----------------
// [B,1,32,32] -> [B,6,28,28]. 3 images/block; task = 2x7 output tile with
// rotated-w row reuse. x tile f64 (fq_f + single cvt at staging), stride 33.
__global__ __launch_bounds__(256) void kconv1(const float* __restrict__ x,
        const float* __restrict__ qw, __hip_bfloat16* __restrict__ c1,
        int nimg_total, double* __restrict__ st1) {
    __shared__ double sxf[3 * 1056];  // 3 x (32 rows x 33) f64 (25.3 KB)
    __shared__ double swd[152];
    __shared__ double sred[6][2];
    int t = threadIdx.x;
    int b0 = blockIdx.x * 3;
    int nimg = nimg_total - b0; if (nimg > 3) nimg = 3;
    for (int i = t; i < nimg * 1024; i += 256) {
        int img = i >> 10, idx = i & 1023;
        sxf[img * 1056 + (idx >> 5) * 33 + (idx & 31)] =
            (double)fq_f(x[(size_t)(b0 + img) * 1024 + idx]);
    }
    if (t < 150) swd[t] = (double)qw[t];
    if (t >= 192 && t < 204) ((double*)sred)[t - 192] = 0.0;
    __syncthreads();
    int ntask = nimg * 336;           // 6 co x 14 rowpairs x 4 colchunks
    for (int task = t; task < ntask; task += 256) {
        int img = task / 336; int rr = task % 336;
        int co = rr / 56; int rem = rr % 56;
        int i0 = (rem >> 2) * 2;      // 0,2,...,26
        int j0 = (rem & 3) * 7;       // 0,7,14,21
        const double* wp = &swd[co * 25];
        double a0[7], a1[7];
        #pragma unroll
        for (int j = 0; j < 7; ++j) { a0[j] = 0.0; a1[j] = 0.0; }
        double wr[5], wq[5];
        #pragma unroll
        for (int u = 0; u < 6; ++u) {
            const double* xr = &sxf[img * 1056 + (i0 + u) * 33 + j0];
            double xv[11];
            #pragma unroll
            for (int k = 0; k < 11; ++k) xv[k] = xr[k];
            if (u < 5) {
                #pragma unroll
                for (int tt = 0; tt < 5; ++tt) wr[tt] = wp[u * 5 + tt];
                #pragma unroll
                for (int j = 0; j < 7; ++j)
                    a0[j] = fma(xv[j], wr[0], fma(xv[j+1], wr[1], fma(xv[j+2], wr[2],
                            fma(xv[j+3], wr[3], fma(xv[j+4], wr[4], a0[j])))));
            }
            if (u >= 1) {
                #pragma unroll
                for (int j = 0; j < 7; ++j)
                    a1[j] = fma(xv[j], wq[0], fma(xv[j+1], wq[1], fma(xv[j+2], wq[2],
                            fma(xv[j+3], wq[3], fma(xv[j+4], wq[4], a1[j])))));
            }
            #pragma unroll
            for (int tt = 0; tt < 5; ++tt) wq[tt] = wr[tt];   // SSA rotate
        }
        size_t base = ((size_t)(b0 + img) * 6 + co) * 784 + (size_t)i0 * 28 + j0;
        double s = 0.0, s2 = 0.0;
        #pragma unroll
        for (int j = 0; j < 7; ++j) {
            double q0 = fq_d(a0[j]), q1 = fq_d(a1[j]);
            ((unsigned short*)c1)[base + j]      = bfbits(q0);
            ((unsigned short*)c1)[base + 28 + j] = bfbits(q1);
            s += q0 + q1; s2 += q0 * q0 + q1 * q1;
        }
        atomicAdd(&sred[co][0], s);
        atomicAdd(&sred[co][1], s2);
    }
    __syncthreads();
    if (t < 12) atomicAdd(&st1[t * 32 + (blockIdx.x & 31)], ((double*)sred)[t]);
}

// ---------------- finalize BN1 from 32-binned stats ----------------
__global__ void kfinal(const double* __restrict__ st, double* __restrict__ mr,
                       int C, double N) {
    int c = threadIdx.x;
    if (c < C) {
        double s = 0.0, s2 = 0.0;
        for (int b = 0; b < 32; ++b) { s += st[c * 64 + b]; s2 += st[c * 64 + 32 + b]; }
        double m = s / N;
        double v = s2 / N - m * m;
        mr[2 * c] = m;
        mr[2 * c + 1] = 1.0 / sqrt(v + 1e-5);
    }
}

// ---------------- bn1 + fq + relu + 2x2 pool (monotone single-fq) ----------
__global__ __launch_bounds__(256) void kpool1(const __hip_bfloat16* __restrict__ c1,
        const double* __restrict__ mr1, const float* __restrict__ g1,
        const float* __restrict__ be1, __hip_bfloat16* __restrict__ p1) {
    int idx = blockIdx.x * 256 + threadIdx.x;   // pair-task: B*6*14*7
    int pp = idx % 7;  int t1 = idx / 7;
    int ph = t1 % 14;  int t2 = t1 / 14;
    int c  = t2 % 6;   int b  = t2 / 6;
    double m = mr1[2 * c], r = mr1[2 * c + 1];
    double gg = (double)g1[c], bb = (double)be1[c];
    bool useMax = (r * gg) >= 0.0;              // selection only
    const __hip_bfloat16* src = c1 + (((size_t)b * 6 + c) * 28 + 2 * ph) * 28 + 4 * pp;
    ushort4 u0 = *(const ushort4*)src;
    ushort4 u1 = *(const ushort4*)(src + 28);
    float f0 = bfval(u0.x), f1 = bfval(u0.y);
    float f2 = bfval(u0.z), f3 = bfval(u0.w);
    float f4 = bfval(u1.x), f5 = bfval(u1.y);
    float f6 = bfval(u1.z), f7 = bfval(u1.w);
    float va = useMax ? fmaxf(fmaxf(f0, f1), fmaxf(f4, f5))
                      : fminf(fminf(f0, f1), fminf(f4, f5));
    float vb = useMax ? fmaxf(fmaxf(f2, f3), fmaxf(f6, f7))
                      : fminf(fminf(f2, f3), fminf(f6, f7));
    double qa = fq_d((((double)va - m) * r) * gg + bb);
    double qb = fq_d((((double)vb - m) * r) * gg + bb);
    qa = fmax(qa, 0.0); qb = fmax(qb, 0.0);
    ushort2 pk; pk.x = bfbits(qa); pk.y = bfbits(qb);
    *(ushort2*)&p1[((size_t)b * 6 + c) * 196 + ph * 14 + 2 * pp] = pk;
}

// ---------------- conv2 as implicit GEMM on v_mfma_f64_16x16x4_f64 --------
// [B,6,14,14] -> [B,100,16] (position-major output). 8 images/block,
// 512 thr = 8 waves, grid 1024 (low-traffic geometry). M = 800 positions
// (50 exact 16-tiles), N = 16 co, K = 152 (150 + 2 pad).
// k-mapping k = 4m + c (2-way bank-benign). r20: soff[152] LDS table
// (tile-invariant patch offsets; pad k>=150 -> 0, weight exactly 0 -> no
// clamp) replaces per-iteration magic-div arithmetic (~6 VALU/pair vs ~30).
// ILP-2 chains/tile. Weights f32 staged coalesced (LDS-BW budget). LDS-
// bounce 512B stores (r17). D-side mapping PROBED at runtime (r13-verified).
__global__ __launch_bounds__(512) void kconv2(const __hip_bfloat16* __restrict__ p1,
        const float* __restrict__ qw2t, __hip_bfloat16* __restrict__ c2,
        double* __restrict__ st2) {
    __shared__ float sxf[9408];        // 8 x [6][14][14] f32 (exact grid vals)
    __shared__ float swf[2432];        // [152][16] f32 weights, k-major (exact)
    __shared__ int soff[152];          // k -> x-tile offset (tile-invariant)
    __shared__ unsigned short sep[8][256];  // per-wave 16x16 bf16 out tile
    __shared__ double sred[16][2];
    int t = threadIdx.x;
    int b0 = blockIdx.x * 8;
    // stage x: 9408 bf16 -> f32, vectorized ushort4 (8B, coalesced)
    const ushort4* srcp = (const ushort4*)(p1 + (size_t)b0 * 1176);
    for (int i = t; i < 2352; i += 512) {
        ushort4 u = srcp[i];
        float* d = &sxf[4 * i];
        d[0] = bfval(u.x);
        d[1] = bfval(u.y);
        d[2] = bfval(u.z);
        d[3] = bfval(u.w);
    }
    // stage weights: pure coalesced copy (608 x float4, L2-resident)
    {
        const float4* wsrc = (const float4*)qw2t;
        float4* wdst = (float4*)swf;
        for (int i = t; i < 608; i += 512) wdst[i] = wsrc[i];
    }
    if (t < 152)
        soff[t] = (t < 150) ? (t / 25) * 196 + ((t % 25) / 5) * 14 + (t % 5) : 0;
    if (t < 32) ((double*)sred)[t] = 0.0;
    __syncthreads();

    int l = t & 63, w = t >> 6;        // lane, wave (0..7)
    int c = l >> 4, r16 = l & 15;      // k-group / {A-row,B-col} staging index

    // ---- layout probes (exact small-int arithmetic, 2 MFMAs) ----
    d4 pz = {0.0, 0.0, 0.0, 0.0};
    d4 prow = __builtin_amdgcn_mfma_f64_16x16x4f64((double)r16, 0.25, pz, 0, 0, 0);
    d4 pcol = __builtin_amdgcn_mfma_f64_16x16x4f64(1.0, 0.25 * (double)r16, pz, 0, 0, 0);
    int rowidx[4], colidx[4];
    #pragma unroll
    for (int j = 0; j < 4; ++j) { rowidx[j] = (int)prow[j]; colidx[j] = (int)pcol[j]; }

    unsigned short* myep = sep[w];
    double ls = 0.0, ls2 = 0.0;        // per-lane stats (col fixed per lane)
    int co0 = colidx[0];
    for (int tile = w; tile < 50; tile += 8) {
        int pos = tile * 16 + r16;     // A-row (staging) for this lane
        int abase = (pos / 100) * 1176 + ((pos % 100) / 10) * 14 + (pos % 10);
        d4 a0 = {0.0, 0.0, 0.0, 0.0}, a1 = {0.0, 0.0, 0.0, 0.0};
        #pragma unroll
        for (int s = 0; s < 19; ++s) {
            int k0 = 4 * s + c;              // chain 0: m = s
            int k1 = 4 * (s + 19) + c;       // chain 1: m = s + 19
            // pad slots (k>=150) have soff 0 and weight exactly 0 -> 0.
            double x0 = (double)sxf[abase + soff[k0]];
            double x1 = (double)sxf[abase + soff[k1]];
            double w0 = (double)swf[k0 * 16 + r16];
            double w1 = (double)swf[k1 * 16 + r16];
            a0 = __builtin_amdgcn_mfma_f64_16x16x4f64(x0, w0, a0, 0, 0, 0);
            a1 = __builtin_amdgcn_mfma_f64_16x16x4f64(x1, w1, a1, 0, 0, 0);
        }
        // epilogue: fq + stats; assemble tile in LDS (probed mapping), then
        // ONE coalesced 512B wave store (c2 tile region is contiguous).
        #pragma unroll
        for (int j = 0; j < 4; ++j) {
            double q = fq_d(a0[j] + a1[j]);
            myep[rowidx[j] * 16 + colidx[j]] = bfbits(q);
            ls += q; ls2 += q * q;
        }
        ushort4 v = *(const ushort4*)&myep[l * 4];   // wave-internal, in-order
        *(ushort4*)((unsigned short*)c2 + ((size_t)b0 * 100 + tile * 16) * 16 + l * 4) = v;
    }
    atomicAdd(&sred[co0][0], ls);
    atomicAdd(&sred[co0][1], ls2);
    __syncthreads();
    if (t < 32) atomicAdd(&st2[t * 32 + (blockIdx.x & 31)], ((double*)sred)[t]);
}

// ---------------- fc1: fused bn2-finalize + bn2/fq/relu/pool staging -------
// BT=8 (1024 blocks): c2 [B,100,16] position-major. Pool reads global
// directly with c-fastest map: 16 consecutive channels per 16-thread
// cluster -> 32B-contiguous loads. LDS 25.9KB -> 6 blocks/CU.
__global__ __launch_bounds__(256) void kfc1(const __hip_bfloat16* __restrict__ c2,
        const double* __restrict__ st2, const float* __restrict__ g2,
        const float* __restrict__ be2, const float* __restrict__ Wt,
        const float* __restrict__ qb, __hip_bfloat16* __restrict__ outb) {
    constexpr int IN = 400, OUT = 120, OUTP = 128, ROWS = 4, BT = 8;
    __shared__ double sx[BT][IN];
    __shared__ double sbn[16][4];
    int t = threadIdx.x;
    int b0 = blockIdx.x * BT;
    if (t < 16) {                       // inline bn2 finalize from stat bins
        double s = 0.0, s2 = 0.0;
        for (int b = 0; b < 32; ++b) { s += st2[t * 64 + b]; s2 += st2[t * 64 + 32 + b]; }
        double m = s / (819200.0);      // 8192*100
        double v = s2 / (819200.0) - m * m;
        sbn[t][0] = m; sbn[t][1] = 1.0 / sqrt(v + 1e-5);
        sbn[t][2] = (double)g2[t]; sbn[t][3] = (double)be2[t];
    }
    __syncthreads();
    for (int i = t; i < BT * IN; i += 256) {
        int cc = i & 15;                // channel fastest (coalesced)
        int rem = (i >> 4) % 25;        // pooled position
        int r = i / 400;                // image row within tile
        int ph = rem / 5, pw = rem % 5;
        const __hip_bfloat16* src = c2 + ((size_t)(b0 + r) * 100 + 20 * ph + 2 * pw) * 16 + cc;
        double m = sbn[cc][0], rr = sbn[cc][1], gg = sbn[cc][2], bb = sbn[cc][3];
        float f0 = __bfloat162float(src[0]),   f1 = __bfloat162float(src[16]);
        float f2 = __bfloat162float(src[160]), f3 = __bfloat162float(src[176]);
        bool useMax = (rr * gg) >= 0.0;
        float v = useMax ? fmaxf(fmaxf(f0, f1), fmaxf(f2, f3))
                         : fminf(fminf(f0, f1), fminf(f2, f3));
        double q = fq_d((((double)v - m) * rr) * gg + bb);
        sx[r][cc * 25 + rem] = fmax(q, 0.0);
    }
    __syncthreads();
    int o = t % OUTP;
    int g = t / OUTP;
    double acc[ROWS];
    double bias = (o < OUT) ? (double)qb[o] : 0.0;
    #pragma unroll
    for (int r = 0; r < ROWS; ++r) acc[r] = bias;
    #pragma unroll 4
    for (int k = 0; k < IN; ++k) {
        double w = (double)Wt[k * OUTP + o];   // coalesced, L2-resident
        #pragma unroll
        for (int r = 0; r < ROWS; ++r)
            acc[r] = fma(sx[g * ROWS + r][k], w, acc[r]);
    }
    if (o < OUT) {
        #pragma unroll
        for (int r = 0; r < ROWS; ++r) {
            double q = fq_d(acc[r]);
            if (q < 0.0) q = 0.0;
            outb[(size_t)(b0 + g * ROWS + r) * OUT + o] = __float2bfloat16((float)q);
        }
    }
}

// ---------------- fused fc2+fc3: a1 [B,120] -> out [B,10] ----------------
__global__ __launch_bounds__(256) void kfc23(const __hip_bfloat16* __restrict__ a1,
        const float* __restrict__ Wt2, const float* __restrict__ qfb2,
        const float* __restrict__ Wt3, const float* __restrict__ qfb3,
        float* __restrict__ out) {
    __shared__ double sx1[16][120];
    __shared__ double s2[16][84];
    int t = threadIdx.x;
    int b0 = blockIdx.x * 16;
    for (int i = t; i < 16 * 120; i += 256) {
        int r = i / 120, k = i % 120;
        sx1[r][k] = (double)__bfloat162float(a1[(size_t)(b0 + r) * 120 + k]);
    }
    __syncthreads();
    {   // fc2: 2 groups x 8 rows x 128 output lanes
        int o = t % 128, g = t / 128;
        double acc[8];
        double bias = (o < 84) ? (double)qfb2[o] : 0.0;
        #pragma unroll
        for (int r = 0; r < 8; ++r) acc[r] = bias;
        #pragma unroll 4
        for (int k = 0; k < 120; ++k) {
            double w = (double)Wt2[k * 128 + o];
            #pragma unroll
            for (int r = 0; r < 8; ++r)
                acc[r] = fma(sx1[g * 8 + r][k], w, acc[r]);
        }
        if (o < 84) {
            #pragma unroll
            for (int r = 0; r < 8; ++r) {
                double q = fq_d(acc[r]);
                s2[g * 8 + r][o] = fmax(q, 0.0);
            }
        }
    }
    __syncthreads();
    {   // fc3: 16 rows x 16 output lanes (10 used)
        int o = t % 16, g = t / 16;
        double acc = (o < 10) ? (double)qfb3[o] : 0.0;
        #pragma unroll 4
        for (int k = 0; k < 84; ++k)
            acc = fma(s2[g][k], (double)Wt3[k * 16 + o], acc);
        if (o < 10)
            out[(size_t)(b0 + g) * 10 + o] = (float)fq_d(acc);
    }
}

// ---------------------------------------------------------------------------
extern "C" void kernel_launch(void* const* d_in, const int* in_sizes, int n_in,
                              void* d_out, int out_size, void* d_ws, size_t ws_size,
                              hipStream_t stream) {
    const float* x   = (const float*)d_in[0];
    const float* w1  = (const float*)d_in[1];
    const float* g1  = (const float*)d_in[2];
    const float* be1 = (const float*)d_in[3];
    const float* w2  = (const float*)d_in[4];
    const float* g2  = (const float*)d_in[5];
    const float* be2 = (const float*)d_in[6];
    const float* fw1 = (const float*)d_in[7];
    const float* fb1 = (const float*)d_in[8];
    const float* fw2 = (const float*)d_in[9];
    const float* fb2 = (const float*)d_in[10];
    const float* fw3 = (const float*)d_in[11];
    const float* fb3 = (const float*)d_in[12];

    char* ws = (char*)d_ws;
    double* stats1 = (double*)(ws + 0);      // [6][2][32] dbl
    double* stats2 = (double*)(ws + 3072);   // [16][2][32] dbl (ends 11264)
    double* mr1    = (double*)(ws + 11264);  // 12 dbl
    float* qw1  = (float*)(ws + 12288);
    float* qw2t = (float*)(ws + 13312);      // [152][16] f32, ends 23040
    float* qfb1 = (float*)(ws + 23040);
    float* qfb2 = (float*)(ws + 23552);
    float* qfb3 = (float*)(ws + 24064);
    float* Wt1  = (float*)(ws + 24576);      // 400*128
    float* Wt2  = (float*)(ws + 229376);     // 120*128
    float* Wt3  = (float*)(ws + 290816);     // 84*16
    __hip_bfloat16* c1 = (__hip_bfloat16*)(ws + 303104);      // [B,6,28,28] 77.1 MB
    __hip_bfloat16* p1 = (__hip_bfloat16*)(ws + 77373440);    // [B,6,14,14] 19.3 MB
    __hip_bfloat16* c2 = (__hip_bfloat16*)(ws + 303104);      // [B,100,16] (c1 dead)
    __hip_bfloat16* a1 = (__hip_bfloat16*)(ws + 303104 + 26214400); // [B,120]

    hipMemsetAsync(ws, 0, 11264, stream);

    kprep<<<(PREP_TOTAL + 255) / 256, 256, 0, stream>>>(
        w1, w2, fb1, fb2, fb3, fw1, fw2, fw3,
        qw1, qw2t, qfb1, qfb2, qfb3, Wt1, Wt2, Wt3);

    // conv1 + fq + stats -> c1   (3 images/block, 2x7 tiles, f64 LDS)
    kconv1<<<(BATCH + 2) / 3, 256, 0, stream>>>(x, qw1, c1, BATCH, stats1);
    kfinal<<<1, 32, 0, stream>>>(stats1, mr1, 6, (double)BATCH * 784.0);
    // bn1 + fq + relu + pool -> p1
    kpool1<<<BATCH * 6 * 14 * 7 / 256, 256, 0, stream>>>(c1, mr1, g1, be1, p1);
    // conv2 via f64 MFMA implicit GEMM (soff table, 8-wave blocks) -> c2
    kconv2<<<BATCH / 8, 512, 0, stream>>>(p1, qw2t, c2, stats2);
    // fc1 (inline bn2 finalize + fused pool staging, +relu) -> a1 [B,120]
    kfc1<<<BATCH / 8, 256, 0, stream>>>(c2, stats2, g2, be2, Wt1, qfb1, a1);
    // fused fc2+fc3 -> d_out [B,10] float
    kfc23<<<BATCH / 16, 256, 0, stream>>>(a1, Wt2, qfb2, Wt3, qfb3, (float*)d_out);
}

// Round 10
// 395.369 us; speedup vs baseline: 1.0204x; 1.0204x over previous
//
#include <hip/hip_runtime.h>
#include <hip/hip_bf16.h>

// ---------------------------------------------------------------------------
// QLenet forward, exact-math strategy:
//   All fq() outputs are e5m2 grid values (<=3 significant bits). Products of
//   two grid values have <=6-bit mantissas; dot sums (<=400 terms, bounded
//   exponent span) are EXACT in f64 -> order-independent -> matches float64
//   numpy reference. Intermediates stored as bf16 (exact for grid values);
//   LDS tiles hold f32 (exact), accumulation stays f64.
// Round 20 -> 21:
//   * r20: kconv2 soff-table WIN (~105us, out of top-5). kconv1 f64-staging
//     REGRESSED (120->142us): conflicts 1.04e7->1.60e7 (f64 doubles bank
//     footprint at stride 33); VALUBusy fell 55->44 but LDS replaced cvt as
//     limiter at a worse rate. Reverted.
//   * r21: kconv1 = r19 f32 staging + the r19 TLP lever: 512 thr / 6 img /
//     1366 blocks (LDS 26.6KB, >=2 waves/SIMD at any residency). Same
//     per-thread work; predict VALUBusy 55->75%+, dur -> 80-95us.
// ---------------------------------------------------------------------------

#define BATCH 8192

typedef double d4 __attribute__((ext_vector_type(4)));

// fq on f64: round to FP(e5m2) nearest-even, subnormal granule 2^-16,
// clip +-57344. Integer RNE on the mantissa; carry propagates into exponent.
__device__ __forceinline__ double fq_d(double x) {
    long long b = __double_as_longlong(x);
    long long ab = b & 0x7fffffffffffffffLL;
    if (ab == 0) return x;                       // +-0 preserved
    double q;
    if (ab >= 0x3F10000000000000LL) {            // |x| >= 2^-14
        long long r = b + 0x0001FFFFFFFFFFFFLL + ((b >> 50) & 1LL);
        r &= 0xFFFC000000000000LL;
        q = __longlong_as_double(r);
        q = fmin(fmax(q, -57344.0), 57344.0);
    } else {                                     // subnormal grid: 2^-16
        q = rint(x * 65536.0) * 1.52587890625e-05;
    }
    return q;
}

// fq on f32 input values (exact f32 -> same e5m2 result as the f64 path).
__device__ __forceinline__ float fq_f(float x) {
    int b = __float_as_int(x);
    int ab = b & 0x7fffffff;
    if (ab == 0) return x;
    float q;
    if (ab >= 0x38800000) {                      // |x| >= 2^-14
        int r = b + 0x000FFFFF + ((b >> 21) & 1);
        r &= 0xFFE00000;                         // sign+exp+2 mantissa bits
        q = __int_as_float(r);
        q = fminf(fmaxf(q, -57344.0f), 57344.0f);
    } else {
        q = rintf(x * 65536.0f) * 1.52587890625e-05f;
    }
    return q;
}

__device__ __forceinline__ unsigned short bfbits(double q) {
    __hip_bfloat16 h = __float2bfloat16((float)q);   // exact for grid values
    return *(unsigned short*)&h;
}

__device__ __forceinline__ float bfval(unsigned short u) {
    return __bfloat162float(*(__hip_bfloat16*)&u);
}

// ---------------- merged prep (all f32-path fq) ----------------
// qw2t: conv2 weights pre-transposed to [152][16] f32 (k-major, zero-padded)
// so kconv2's LDS staging is a pure coalesced copy.
__global__ void kprep(const float* __restrict__ w1, const float* __restrict__ w2,
                      const float* __restrict__ fb1, const float* __restrict__ fb2,
                      const float* __restrict__ fb3, const float* __restrict__ fw1,
                      const float* __restrict__ fw2, const float* __restrict__ fw3,
                      float* __restrict__ qw1, float* __restrict__ qw2t,
                      float* __restrict__ qfb1, float* __restrict__ qfb2,
                      float* __restrict__ qfb3, float* __restrict__ Wt1,
                      float* __restrict__ Wt2, float* __restrict__ Wt3) {
    int i = blockIdx.x * 256 + threadIdx.x;
    if (i < 150) { qw1[i] = fq_f(w1[i]); return; }
    i -= 150;
    if (i < 2432) { int k = i >> 4, co = i & 15;
        qw2t[i] = (k < 150) ? fq_f(w2[co * 150 + k]) : 0.0f; return; }
    i -= 2432;
    if (i < 120) { qfb1[i] = fq_f(fb1[i]); return; }
    i -= 120;
    if (i < 84) { qfb2[i] = fq_f(fb2[i]); return; }
    i -= 84;
    if (i < 10) { qfb3[i] = fq_f(fb3[i]); return; }
    i -= 10;
    if (i < 51200) { int k = i / 128, o = i % 128;
        Wt1[i] = (o < 120) ? fq_f(fw1[o * 400 + k]) : 0.0f; return; }
    i -= 51200;
    if (i < 15360) { int k = i / 128, o = i % 128;
        Wt2[i] = (o < 84) ? fq_f(fw2[o * 120 + k]) : 0.0f; return; }
    i -= 15360;
    if (i < 1344) { int k = i / 16, o = i % 16;
        Wt3[i] = (o < 10) ? fq_f(fw3[o * 84 + k]) : 0.0f; return; }
}
#define PREP_TOTAL (150 + 2432 + 120 + 84 + 10 + 51200 + 15360 + 1344)

// ---------------- conv1 + fq + fused BN stats ----------------
// [B,1,32,32] -> [B,6,28,28]. r21: 6 images/block, 512 thr = 8 waves
// (TLP lever from r19); x tile f32 (fq_f staging), stride 33; task =
// 2x7 output tile with rotated-w row reuse (f64 cvt on read, r19-verified).
__global__ __launch_bounds__(512) void kconv1(const float* __restrict__ x,
        const float* __restrict__ qw, __hip_bfloat16* __restrict__ c1,
        int nimg_total, double* __restrict__ st1) {
    __shared__ float sxf[6 * 1056];   // 6 x (32 rows x 33) f32 (25.3 KB)
    __shared__ double swd[152];
    __shared__ double sred[6][2];
    int t = threadIdx.x;
    int b0 = blockIdx.x * 6;
    int nimg = nimg_total - b0; if (nimg > 6) nimg = 6;
    for (int i = t; i < nimg * 1024; i += 512) {
        int img = i >> 10, idx = i & 1023;
        sxf[img * 1056 + (idx >> 5) * 33 + (idx & 31)] =
            fq_f(x[(size_t)(b0 + img) * 1024 + idx]);
    }
    if (t < 150) swd[t] = (double)qw[t];
    if (t >= 192 && t < 204) ((double*)sred)[t - 192] = 0.0;
    __syncthreads();
    int ntask = nimg * 336;           // 6 co x 14 rowpairs x 4 colchunks
    for (int task = t; task < ntask; task += 512) {
        int img = task / 336; int rr = task % 336;
        int co = rr / 56; int rem = rr % 56;
        int i0 = (rem >> 2) * 2;      // 0,2,...,26
        int j0 = (rem & 3) * 7;       // 0,7,14,21
        const double* wp = &swd[co * 25];
        double a0[7], a1[7];
        #pragma unroll
        for (int j = 0; j < 7; ++j) { a0[j] = 0.0; a1[j] = 0.0; }
        double wr[5], wq[5];
        #pragma unroll
        for (int u = 0; u < 6; ++u) {
            const float* xr = &sxf[img * 1056 + (i0 + u) * 33 + j0];
            double xv[11];
            #pragma unroll
            for (int k = 0; k < 11; ++k) xv[k] = (double)xr[k];
            if (u < 5) {
                #pragma unroll
                for (int tt = 0; tt < 5; ++tt) wr[tt] = wp[u * 5 + tt];
                #pragma unroll
                for (int j = 0; j < 7; ++j)
                    a0[j] = fma(xv[j], wr[0], fma(xv[j+1], wr[1], fma(xv[j+2], wr[2],
                            fma(xv[j+3], wr[3], fma(xv[j+4], wr[4], a0[j])))));
            }
            if (u >= 1) {
                #pragma unroll
                for (int j = 0; j < 7; ++j)
                    a1[j] = fma(xv[j], wq[0], fma(xv[j+1], wq[1], fma(xv[j+2], wq[2],
                            fma(xv[j+3], wq[3], fma(xv[j+4], wq[4], a1[j])))));
            }
            #pragma unroll
            for (int tt = 0; tt < 5; ++tt) wq[tt] = wr[tt];   // SSA rotate
        }
        size_t base = ((size_t)(b0 + img) * 6 + co) * 784 + (size_t)i0 * 28 + j0;
        double s = 0.0, s2 = 0.0;
        #pragma unroll
        for (int j = 0; j < 7; ++j) {
            double q0 = fq_d(a0[j]), q1 = fq_d(a1[j]);
            ((unsigned short*)c1)[base + j]      = bfbits(q0);
            ((unsigned short*)c1)[base + 28 + j] = bfbits(q1);
            s += q0 + q1; s2 += q0 * q0 + q1 * q1;
        }
        atomicAdd(&sred[co][0], s);
        atomicAdd(&sred[co][1], s2);
    }
    __syncthreads();
    if (t < 12) atomicAdd(&st1[t * 32 + (blockIdx.x & 31)], ((double*)sred)[t]);
}

// ---------------- finalize BN1 from 32-binned stats ----------------
__global__ void kfinal(const double* __restrict__ st, double* __restrict__ mr,
                       int C, double N) {
    int c = threadIdx.x;
    if (c < C) {
        double s = 0.0, s2 = 0.0;
        for (int b = 0; b < 32; ++b) { s += st[c * 64 + b]; s2 += st[c * 64 + 32 + b]; }
        double m = s / N;
        double v = s2 / N - m * m;
        mr[2 * c] = m;
        mr[2 * c + 1] = 1.0 / sqrt(v + 1e-5);
    }
}

// ---------------- bn1 + fq + relu + 2x2 pool (monotone single-fq) ----------
__global__ __launch_bounds__(256) void kpool1(const __hip_bfloat16* __restrict__ c1,
        const double* __restrict__ mr1, const float* __restrict__ g1,
        const float* __restrict__ be1, __hip_bfloat16* __restrict__ p1) {
    int idx = blockIdx.x * 256 + threadIdx.x;   // pair-task: B*6*14*7
    int pp = idx % 7;  int t1 = idx / 7;
    int ph = t1 % 14;  int t2 = t1 / 14;
    int c  = t2 % 6;   int b  = t2 / 6;
    double m = mr1[2 * c], r = mr1[2 * c + 1];
    double gg = (double)g1[c], bb = (double)be1[c];
    bool useMax = (r * gg) >= 0.0;              // selection only
    const __hip_bfloat16* src = c1 + (((size_t)b * 6 + c) * 28 + 2 * ph) * 28 + 4 * pp;
    ushort4 u0 = *(const ushort4*)src;
    ushort4 u1 = *(const ushort4*)(src + 28);
    float f0 = bfval(u0.x), f1 = bfval(u0.y);
    float f2 = bfval(u0.z), f3 = bfval(u0.w);
    float f4 = bfval(u1.x), f5 = bfval(u1.y);
    float f6 = bfval(u1.z), f7 = bfval(u1.w);
    float va = useMax ? fmaxf(fmaxf(f0, f1), fmaxf(f4, f5))
                      : fminf(fminf(f0, f1), fminf(f4, f5));
    float vb = useMax ? fmaxf(fmaxf(f2, f3), fmaxf(f6, f7))
                      : fminf(fminf(f2, f3), fminf(f6, f7));
    double qa = fq_d((((double)va - m) * r) * gg + bb);
    double qb = fq_d((((double)vb - m) * r) * gg + bb);
    qa = fmax(qa, 0.0); qb = fmax(qb, 0.0);
    ushort2 pk; pk.x = bfbits(qa); pk.y = bfbits(qb);
    *(ushort2*)&p1[((size_t)b * 6 + c) * 196 + ph * 14 + 2 * pp] = pk;
}

// ---------------- conv2 as implicit GEMM on v_mfma_f64_16x16x4_f64 --------
// [B,6,14,14] -> [B,100,16] (position-major output). 8 images/block,
// 512 thr = 8 waves, grid 1024 (low-traffic geometry). M = 800 positions
// (50 exact 16-tiles), N = 16 co, K = 152 (150 + 2 pad).
// k-mapping k = 4m + c (2-way bank-benign). soff[152] LDS table
// (tile-invariant patch offsets; pad k>=150 -> 0, weight exactly 0).
// ILP-2 chains/tile. Weights f32 staged coalesced. LDS-bounce 512B stores.
// D-side mapping PROBED at runtime (r13-verified).
__global__ __launch_bounds__(512) void kconv2(const __hip_bfloat16* __restrict__ p1,
        const float* __restrict__ qw2t, __hip_bfloat16* __restrict__ c2,
        double* __restrict__ st2) {
    __shared__ float sxf[9408];        // 8 x [6][14][14] f32 (exact grid vals)
    __shared__ float swf[2432];        // [152][16] f32 weights, k-major (exact)
    __shared__ int soff[152];          // k -> x-tile offset (tile-invariant)
    __shared__ unsigned short sep[8][256];  // per-wave 16x16 bf16 out tile
    __shared__ double sred[16][2];
    int t = threadIdx.x;
    int b0 = blockIdx.x * 8;
    // stage x: 9408 bf16 -> f32, vectorized ushort4 (8B, coalesced)
    const ushort4* srcp = (const ushort4*)(p1 + (size_t)b0 * 1176);
    for (int i = t; i < 2352; i += 512) {
        ushort4 u = srcp[i];
        float* d = &sxf[4 * i];
        d[0] = bfval(u.x);
        d[1] = bfval(u.y);
        d[2] = bfval(u.z);
        d[3] = bfval(u.w);
    }
    // stage weights: pure coalesced copy (608 x float4, L2-resident)
    {
        const float4* wsrc = (const float4*)qw2t;
        float4* wdst = (float4*)swf;
        for (int i = t; i < 608; i += 512) wdst[i] = wsrc[i];
    }
    if (t < 152)
        soff[t] = (t < 150) ? (t / 25) * 196 + ((t % 25) / 5) * 14 + (t % 5) : 0;
    if (t < 32) ((double*)sred)[t] = 0.0;
    __syncthreads();

    int l = t & 63, w = t >> 6;        // lane, wave (0..7)
    int c = l >> 4, r16 = l & 15;      // k-group / {A-row,B-col} staging index

    // ---- layout probes (exact small-int arithmetic, 2 MFMAs) ----
    d4 pz = {0.0, 0.0, 0.0, 0.0};
    d4 prow = __builtin_amdgcn_mfma_f64_16x16x4f64((double)r16, 0.25, pz, 0, 0, 0);
    d4 pcol = __builtin_amdgcn_mfma_f64_16x16x4f64(1.0, 0.25 * (double)r16, pz, 0, 0, 0);
    int rowidx[4], colidx[4];
    #pragma unroll
    for (int j = 0; j < 4; ++j) { rowidx[j] = (int)prow[j]; colidx[j] = (int)pcol[j]; }

    unsigned short* myep = sep[w];
    double ls = 0.0, ls2 = 0.0;        // per-lane stats (col fixed per lane)
    int co0 = colidx[0];
    for (int tile = w; tile < 50; tile += 8) {
        int pos = tile * 16 + r16;     // A-row (staging) for this lane
        int abase = (pos / 100) * 1176 + ((pos % 100) / 10) * 14 + (pos % 10);
        d4 a0 = {0.0, 0.0, 0.0, 0.0}, a1 = {0.0, 0.0, 0.0, 0.0};
        #pragma unroll
        for (int s = 0; s < 19; ++s) {
            int k0 = 4 * s + c;              // chain 0: m = s
            int k1 = 4 * (s + 19) + c;       // chain 1: m = s + 19
            // pad slots (k>=150) have soff 0 and weight exactly 0 -> 0.
            double x0 = (double)sxf[abase + soff[k0]];
            double x1 = (double)sxf[abase + soff[k1]];
            double w0 = (double)swf[k0 * 16 + r16];
            double w1 = (double)swf[k1 * 16 + r16];
            a0 = __builtin_amdgcn_mfma_f64_16x16x4f64(x0, w0, a0, 0, 0, 0);
            a1 = __builtin_amdgcn_mfma_f64_16x16x4f64(x1, w1, a1, 0, 0, 0);
        }
        // epilogue: fq + stats; assemble tile in LDS (probed mapping), then
        // ONE coalesced 512B wave store (c2 tile region is contiguous).
        #pragma unroll
        for (int j = 0; j < 4; ++j) {
            double q = fq_d(a0[j] + a1[j]);
            myep[rowidx[j] * 16 + colidx[j]] = bfbits(q);
            ls += q; ls2 += q * q;
        }
        ushort4 v = *(const ushort4*)&myep[l * 4];   // wave-internal, in-order
        *(ushort4*)((unsigned short*)c2 + ((size_t)b0 * 100 + tile * 16) * 16 + l * 4) = v;
    }
    atomicAdd(&sred[co0][0], ls);
    atomicAdd(&sred[co0][1], ls2);
    __syncthreads();
    if (t < 32) atomicAdd(&st2[t * 32 + (blockIdx.x & 31)], ((double*)sred)[t]);
}

// ---------------- fc1: fused bn2-finalize + bn2/fq/relu/pool staging -------
// BT=8 (1024 blocks): c2 [B,100,16] position-major. Pool reads global
// directly with c-fastest map: 16 consecutive channels per 16-thread
// cluster -> 32B-contiguous loads. LDS 25.9KB -> 6 blocks/CU.
__global__ __launch_bounds__(256) void kfc1(const __hip_bfloat16* __restrict__ c2,
        const double* __restrict__ st2, const float* __restrict__ g2,
        const float* __restrict__ be2, const float* __restrict__ Wt,
        const float* __restrict__ qb, __hip_bfloat16* __restrict__ outb) {
    constexpr int IN = 400, OUT = 120, OUTP = 128, ROWS = 4, BT = 8;
    __shared__ double sx[BT][IN];
    __shared__ double sbn[16][4];
    int t = threadIdx.x;
    int b0 = blockIdx.x * BT;
    if (t < 16) {                       // inline bn2 finalize from stat bins
        double s = 0.0, s2 = 0.0;
        for (int b = 0; b < 32; ++b) { s += st2[t * 64 + b]; s2 += st2[t * 64 + 32 + b]; }
        double m = s / (819200.0);      // 8192*100
        double v = s2 / (819200.0) - m * m;
        sbn[t][0] = m; sbn[t][1] = 1.0 / sqrt(v + 1e-5);
        sbn[t][2] = (double)g2[t]; sbn[t][3] = (double)be2[t];
    }
    __syncthreads();
    for (int i = t; i < BT * IN; i += 256) {
        int cc = i & 15;                // channel fastest (coalesced)
        int rem = (i >> 4) % 25;        // pooled position
        int r = i / 400;                // image row within tile
        int ph = rem / 5, pw = rem % 5;
        const __hip_bfloat16* src = c2 + ((size_t)(b0 + r) * 100 + 20 * ph + 2 * pw) * 16 + cc;
        double m = sbn[cc][0], rr = sbn[cc][1], gg = sbn[cc][2], bb = sbn[cc][3];
        float f0 = __bfloat162float(src[0]),   f1 = __bfloat162float(src[16]);
        float f2 = __bfloat162float(src[160]), f3 = __bfloat162float(src[176]);
        bool useMax = (rr * gg) >= 0.0;
        float v = useMax ? fmaxf(fmaxf(f0, f1), fmaxf(f2, f3))
                         : fminf(fminf(f0, f1), fminf(f2, f3));
        double q = fq_d((((double)v - m) * rr) * gg + bb);
        sx[r][cc * 25 + rem] = fmax(q, 0.0);
    }
    __syncthreads();
    int o = t % OUTP;
    int g = t / OUTP;
    double acc[ROWS];
    double bias = (o < OUT) ? (double)qb[o] : 0.0;
    #pragma unroll
    for (int r = 0; r < ROWS; ++r) acc[r] = bias;
    #pragma unroll 4
    for (int k = 0; k < IN; ++k) {
        double w = (double)Wt[k * OUTP + o];   // coalesced, L2-resident
        #pragma unroll
        for (int r = 0; r < ROWS; ++r)
            acc[r] = fma(sx[g * ROWS + r][k], w, acc[r]);
    }
    if (o < OUT) {
        #pragma unroll
        for (int r = 0; r < ROWS; ++r) {
            double q = fq_d(acc[r]);
            if (q < 0.0) q = 0.0;
            outb[(size_t)(b0 + g * ROWS + r) * OUT + o] = __float2bfloat16((float)q);
        }
    }
}

// ---------------- fused fc2+fc3: a1 [B,120] -> out [B,10] ----------------
__global__ __launch_bounds__(256) void kfc23(const __hip_bfloat16* __restrict__ a1,
        const float* __restrict__ Wt2, const float* __restrict__ qfb2,
        const float* __restrict__ Wt3, const float* __restrict__ qfb3,
        float* __restrict__ out) {
    __shared__ double sx1[16][120];
    __shared__ double s2[16][84];
    int t = threadIdx.x;
    int b0 = blockIdx.x * 16;
    for (int i = t; i < 16 * 120; i += 256) {
        int r = i / 120, k = i % 120;
        sx1[r][k] = (double)__bfloat162float(a1[(size_t)(b0 + r) * 120 + k]);
    }
    __syncthreads();
    {   // fc2: 2 groups x 8 rows x 128 output lanes
        int o = t % 128, g = t / 128;
        double acc[8];
        double bias = (o < 84) ? (double)qfb2[o] : 0.0;
        #pragma unroll
        for (int r = 0; r < 8; ++r) acc[r] = bias;
        #pragma unroll 4
        for (int k = 0; k < 120; ++k) {
            double w = (double)Wt2[k * 128 + o];
            #pragma unroll
            for (int r = 0; r < 8; ++r)
                acc[r] = fma(sx1[g * 8 + r][k], w, acc[r]);
        }
        if (o < 84) {
            #pragma unroll
            for (int r = 0; r < 8; ++r) {
                double q = fq_d(acc[r]);
                s2[g * 8 + r][o] = fmax(q, 0.0);
            }
        }
    }
    __syncthreads();
    {   // fc3: 16 rows x 16 output lanes (10 used)
        int o = t % 16, g = t / 16;
        double acc = (o < 10) ? (double)qfb3[o] : 0.0;
        #pragma unroll 4
        for (int k = 0; k < 84; ++k)
            acc = fma(s2[g][k], (double)Wt3[k * 16 + o], acc);
        if (o < 10)
            out[(size_t)(b0 + g) * 10 + o] = (float)fq_d(acc);
    }
}

// ---------------------------------------------------------------------------
extern "C" void kernel_launch(void* const* d_in, const int* in_sizes, int n_in,
                              void* d_out, int out_size, void* d_ws, size_t ws_size,
                              hipStream_t stream) {
    const float* x   = (const float*)d_in[0];
    const float* w1  = (const float*)d_in[1];
    const float* g1  = (const float*)d_in[2];
    const float* be1 = (const float*)d_in[3];
    const float* w2  = (const float*)d_in[4];
    const float* g2  = (const float*)d_in[5];
    const float* be2 = (const float*)d_in[6];
    const float* fw1 = (const float*)d_in[7];
    const float* fb1 = (const float*)d_in[8];
    const float* fw2 = (const float*)d_in[9];
    const float* fb2 = (const float*)d_in[10];
    const float* fw3 = (const float*)d_in[11];
    const float* fb3 = (const float*)d_in[12];

    char* ws = (char*)d_ws;
    double* stats1 = (double*)(ws + 0);      // [6][2][32] dbl
    double* stats2 = (double*)(ws + 3072);   // [16][2][32] dbl (ends 11264)
    double* mr1    = (double*)(ws + 11264);  // 12 dbl
    float* qw1  = (float*)(ws + 12288);
    float* qw2t = (float*)(ws + 13312);      // [152][16] f32, ends 23040
    float* qfb1 = (float*)(ws + 23040);
    float* qfb2 = (float*)(ws + 23552);
    float* qfb3 = (float*)(ws + 24064);
    float* Wt1  = (float*)(ws + 24576);      // 400*128
    float* Wt2  = (float*)(ws + 229376);     // 120*128
    float* Wt3  = (float*)(ws + 290816);     // 84*16
    __hip_bfloat16* c1 = (__hip_bfloat16*)(ws + 303104);      // [B,6,28,28] 77.1 MB
    __hip_bfloat16* p1 = (__hip_bfloat16*)(ws + 77373440);    // [B,6,14,14] 19.3 MB
    __hip_bfloat16* c2 = (__hip_bfloat16*)(ws + 303104);      // [B,100,16] (c1 dead)
    __hip_bfloat16* a1 = (__hip_bfloat16*)(ws + 303104 + 26214400); // [B,120]

    hipMemsetAsync(ws, 0, 11264, stream);

    kprep<<<(PREP_TOTAL + 255) / 256, 256, 0, stream>>>(
        w1, w2, fb1, fb2, fb3, fw1, fw2, fw3,
        qw1, qw2t, qfb1, qfb2, qfb3, Wt1, Wt2, Wt3);

    // conv1 + fq + stats -> c1   (6 images/block, 8 waves, f32 LDS)
    kconv1<<<(BATCH + 5) / 6, 512, 0, stream>>>(x, qw1, c1, BATCH, stats1);
    kfinal<<<1, 32, 0, stream>>>(stats1, mr1, 6, (double)BATCH * 784.0);
    // bn1 + fq + relu + pool -> p1
    kpool1<<<BATCH * 6 * 14 * 7 / 256, 256, 0, stream>>>(c1, mr1, g1, be1, p1);
    // conv2 via f64 MFMA implicit GEMM (soff table, 8-wave blocks) -> c2
    kconv2<<<BATCH / 8, 512, 0, stream>>>(p1, qw2t, c2, stats2);
    // fc1 (inline bn2 finalize + fused pool staging, +relu) -> a1 [B,120]
    kfc1<<<BATCH / 8, 256, 0, stream>>>(c2, stats2, g2, be2, Wt1, qfb1, a1);
    // fused fc2+fc3 -> d_out [B,10] float
    kfc23<<<BATCH / 16, 256, 0, stream>>>(a1, Wt2, qfb2, Wt3, qfb3, (float*)d_out);
}

// Round 11
// 378.337 us; speedup vs baseline: 1.0663x; 1.0450x over previous
//
#include <hip/hip_runtime.h>
#include <hip/hip_bf16.h>

// ---------------------------------------------------------------------------
// QLenet forward, exact-math strategy:
//   All fq() outputs are e5m2 grid values (<=3 significant bits). Products of
//   two grid values have <=6-bit mantissas; dot sums (<=400 terms, bounded
//   exponent span) are EXACT in f64 -> order-independent -> matches float64
//   numpy reference. Intermediates stored as bf16 (exact for grid values);
//   LDS tiles hold f32 (exact), accumulation stays f64.
// Round 21 -> 22:
//   * r21: kconv1 TLP lever FAILED (132us @ 512thr vs 120 @ 256thr; occ
//     stuck ~20% in both — not resource-capped, lever abandoned).
//   * Structural fix instead: pool selection sign(r*gg) = sign(g1[c]) is
//     known WITHOUT BN stats (r>0; fq/relu/bn monotone). kconv1 now pools
//     in-epilogue (it already computes fq_d of every output for stats) and
//     writes only pooled raw values praw [B,6,14,14] (19.3 MB) instead of
//     c1 (77 MB). kpool1 -> kbn1: trivial elementwise bn+fq+relu (38.6 MB
//     traffic). Task = 2x14 tile (full pool windows), 512thr x 3img ->
//     one task/thread, single atomics burst.
//   * kconv2 (soff table, 8-wave) kept from r20/21 (~105us).
// ---------------------------------------------------------------------------

#define BATCH 8192

typedef double d4 __attribute__((ext_vector_type(4)));

// fq on f64: round to FP(e5m2) nearest-even, subnormal granule 2^-16,
// clip +-57344. Integer RNE on the mantissa; carry propagates into exponent.
__device__ __forceinline__ double fq_d(double x) {
    long long b = __double_as_longlong(x);
    long long ab = b & 0x7fffffffffffffffLL;
    if (ab == 0) return x;                       // +-0 preserved
    double q;
    if (ab >= 0x3F10000000000000LL) {            // |x| >= 2^-14
        long long r = b + 0x0001FFFFFFFFFFFFLL + ((b >> 50) & 1LL);
        r &= 0xFFFC000000000000LL;
        q = __longlong_as_double(r);
        q = fmin(fmax(q, -57344.0), 57344.0);
    } else {                                     // subnormal grid: 2^-16
        q = rint(x * 65536.0) * 1.52587890625e-05;
    }
    return q;
}

// fq on f32 input values (exact f32 -> same e5m2 result as the f64 path).
__device__ __forceinline__ float fq_f(float x) {
    int b = __float_as_int(x);
    int ab = b & 0x7fffffff;
    if (ab == 0) return x;
    float q;
    if (ab >= 0x38800000) {                      // |x| >= 2^-14
        int r = b + 0x000FFFFF + ((b >> 21) & 1);
        r &= 0xFFE00000;                         // sign+exp+2 mantissa bits
        q = __int_as_float(r);
        q = fminf(fmaxf(q, -57344.0f), 57344.0f);
    } else {
        q = rintf(x * 65536.0f) * 1.52587890625e-05f;
    }
    return q;
}

__device__ __forceinline__ unsigned short bfbits(double q) {
    __hip_bfloat16 h = __float2bfloat16((float)q);   // exact for grid values
    return *(unsigned short*)&h;
}

__device__ __forceinline__ float bfval(unsigned short u) {
    return __bfloat162float(*(__hip_bfloat16*)&u);
}

// ---------------- merged prep (all f32-path fq) ----------------
// qw2t: conv2 weights pre-transposed to [152][16] f32 (k-major, zero-padded)
// so kconv2's LDS staging is a pure coalesced copy.
__global__ void kprep(const float* __restrict__ w1, const float* __restrict__ w2,
                      const float* __restrict__ fb1, const float* __restrict__ fb2,
                      const float* __restrict__ fb3, const float* __restrict__ fw1,
                      const float* __restrict__ fw2, const float* __restrict__ fw3,
                      float* __restrict__ qw1, float* __restrict__ qw2t,
                      float* __restrict__ qfb1, float* __restrict__ qfb2,
                      float* __restrict__ qfb3, float* __restrict__ Wt1,
                      float* __restrict__ Wt2, float* __restrict__ Wt3) {
    int i = blockIdx.x * 256 + threadIdx.x;
    if (i < 150) { qw1[i] = fq_f(w1[i]); return; }
    i -= 150;
    if (i < 2432) { int k = i >> 4, co = i & 15;
        qw2t[i] = (k < 150) ? fq_f(w2[co * 150 + k]) : 0.0f; return; }
    i -= 2432;
    if (i < 120) { qfb1[i] = fq_f(fb1[i]); return; }
    i -= 120;
    if (i < 84) { qfb2[i] = fq_f(fb2[i]); return; }
    i -= 84;
    if (i < 10) { qfb3[i] = fq_f(fb3[i]); return; }
    i -= 10;
    if (i < 51200) { int k = i / 128, o = i % 128;
        Wt1[i] = (o < 120) ? fq_f(fw1[o * 400 + k]) : 0.0f; return; }
    i -= 51200;
    if (i < 15360) { int k = i / 128, o = i % 128;
        Wt2[i] = (o < 84) ? fq_f(fw2[o * 120 + k]) : 0.0f; return; }
    i -= 15360;
    if (i < 1344) { int k = i / 16, o = i % 16;
        Wt3[i] = (o < 10) ? fq_f(fw3[o * 84 + k]) : 0.0f; return; }
}
#define PREP_TOTAL (150 + 2432 + 120 + 84 + 10 + 51200 + 15360 + 1344)

// ---------------- conv1 + fq + stats + inline 2x2 pool ----------------
// [B,1,32,32] -> praw [B,6,14,14] (pooled raw max-or-min of fq'd conv out).
// 3 images/block, 512 thr; task = (img, co, rowpair, half) = 2x14 tile ->
// 7 complete pool windows; 504 tasks -> one task/thread. Selection uses
// sign(g1[co]) only (r>0 always; fq/relu/bn monotone) — no stats needed.
__global__ __launch_bounds__(512) void kconv1(const float* __restrict__ x,
        const float* __restrict__ qw, const float* __restrict__ g1,
        unsigned short* __restrict__ praw, int nimg_total,
        double* __restrict__ st1) {
    __shared__ float sxf[3 * 1056];   // 3 x (32 rows x 33) f32 (12.7 KB)
    __shared__ double swd[152];
    __shared__ float sg1[6];
    __shared__ double sred[6][2];
    int t = threadIdx.x;
    int b0 = blockIdx.x * 3;
    int nimg = nimg_total - b0; if (nimg > 3) nimg = 3;
    for (int i = t; i < nimg * 1024; i += 512) {
        int img = i >> 10, idx = i & 1023;
        sxf[img * 1056 + (idx >> 5) * 33 + (idx & 31)] =
            fq_f(x[(size_t)(b0 + img) * 1024 + idx]);
    }
    if (t < 150) swd[t] = (double)qw[t];
    if (t >= 160 && t < 166) sg1[t - 160] = g1[t - 160];
    if (t >= 192 && t < 204) ((double*)sred)[t - 192] = 0.0;
    __syncthreads();
    int ntask = nimg * 168;           // 6 co x 14 rowpairs x 2 halves
    for (int task = t; task < ntask; task += 512) {
        int img = task / 168; int rr = task % 168;
        int co = rr / 28; int rem = rr % 28;
        int ph = rem >> 1;            // pooled row 0..13
        int half = rem & 1;           // col half 0/1
        int i0 = 2 * ph;              // c1 rows i0, i0+1
        int j0 = half * 14;           // c1 cols j0..j0+13
        const double* wp = &swd[co * 25];
        double a0[14], a1[14];
        #pragma unroll
        for (int j = 0; j < 14; ++j) { a0[j] = 0.0; a1[j] = 0.0; }
        double wr[5], wq[5];
        #pragma unroll
        for (int u = 0; u < 6; ++u) {
            const float* xr = &sxf[img * 1056 + (i0 + u) * 33 + j0];
            double xv[18];
            #pragma unroll
            for (int k = 0; k < 18; ++k) xv[k] = (double)xr[k];
            if (u < 5) {
                #pragma unroll
                for (int tt = 0; tt < 5; ++tt) wr[tt] = wp[u * 5 + tt];
                #pragma unroll
                for (int j = 0; j < 14; ++j)
                    a0[j] = fma(xv[j], wr[0], fma(xv[j+1], wr[1], fma(xv[j+2], wr[2],
                            fma(xv[j+3], wr[3], fma(xv[j+4], wr[4], a0[j])))));
            }
            if (u >= 1) {
                #pragma unroll
                for (int j = 0; j < 14; ++j)
                    a1[j] = fma(xv[j], wq[0], fma(xv[j+1], wq[1], fma(xv[j+2], wq[2],
                            fma(xv[j+3], wq[3], fma(xv[j+4], wq[4], a1[j])))));
            }
            #pragma unroll
            for (int tt = 0; tt < 5; ++tt) wq[tt] = wr[tt];   // SSA rotate
        }
        // epilogue: fq (needed for stats anyway) + stats + 2x2 pool of the
        // fq'd values (max if g1[co]>=0 else min; monotone chain) -> 7 vals.
        double q0[14], q1[14];
        double s = 0.0, s2 = 0.0;
        #pragma unroll
        for (int j = 0; j < 14; ++j) {
            q0[j] = fq_d(a0[j]); q1[j] = fq_d(a1[j]);
            s += q0[j] + q1[j]; s2 += q0[j] * q0[j] + q1[j] * q1[j];
        }
        bool useMax = (sg1[co] >= 0.0f);
        unsigned short* dst = praw + ((size_t)(b0 + img) * 6 + co) * 196 + ph * 14 + half * 7;
        #pragma unroll
        for (int jp = 0; jp < 7; ++jp) {
            double pmax = fmax(fmax(q0[2*jp], q0[2*jp+1]), fmax(q1[2*jp], q1[2*jp+1]));
            double pmin = fmin(fmin(q0[2*jp], q0[2*jp+1]), fmin(q1[2*jp], q1[2*jp+1]));
            dst[jp] = bfbits(useMax ? pmax : pmin);
        }
        atomicAdd(&sred[co][0], s);
        atomicAdd(&sred[co][1], s2);
    }
    __syncthreads();
    if (t < 12) atomicAdd(&st1[t * 32 + (blockIdx.x & 31)], ((double*)sred)[t]);
}

// ---------------- finalize BN1 from 32-binned stats ----------------
__global__ void kfinal(const double* __restrict__ st, double* __restrict__ mr,
                       int C, double N) {
    int c = threadIdx.x;
    if (c < C) {
        double s = 0.0, s2 = 0.0;
        for (int b = 0; b < 32; ++b) { s += st[c * 64 + b]; s2 += st[c * 64 + 32 + b]; }
        double m = s / N;
        double v = s2 / N - m * m;
        mr[2 * c] = m;
        mr[2 * c + 1] = 1.0 / sqrt(v + 1e-5);
    }
}

// ---------------- bn1 + fq + relu on pooled raw values ----------------
// praw [B,6,14,14] -> p1 [B,6,14,14]. Pure elementwise (pool already done
// in kconv1); ushort4 vectorized, 38.6 MB total traffic.
__global__ __launch_bounds__(256) void kbn1(const unsigned short* __restrict__ praw,
        const double* __restrict__ mr1, const float* __restrict__ g1,
        const float* __restrict__ be1, __hip_bfloat16* __restrict__ p1) {
    int idx = blockIdx.x * 256 + threadIdx.x;   // B*6*49 ushort4-tasks
    int cb = idx / 49;                          // b*6 + c
    int c = cb % 6;
    int off = (idx % 49) * 4;
    double m = mr1[2 * c], r = mr1[2 * c + 1];
    double gg = (double)g1[c], bb = (double)be1[c];
    ushort4 u = *(const ushort4*)(praw + (size_t)cb * 196 + off);
    ushort4 o;
    double q;
    q = fq_d((((double)bfval(u.x) - m) * r) * gg + bb); o.x = bfbits(fmax(q, 0.0));
    q = fq_d((((double)bfval(u.y) - m) * r) * gg + bb); o.y = bfbits(fmax(q, 0.0));
    q = fq_d((((double)bfval(u.z) - m) * r) * gg + bb); o.z = bfbits(fmax(q, 0.0));
    q = fq_d((((double)bfval(u.w) - m) * r) * gg + bb); o.w = bfbits(fmax(q, 0.0));
    *(ushort4*)((unsigned short*)p1 + (size_t)cb * 196 + off) = o;
}

// ---------------- conv2 as implicit GEMM on v_mfma_f64_16x16x4_f64 --------
// [B,6,14,14] -> [B,100,16] (position-major output). 8 images/block,
// 512 thr = 8 waves, grid 1024 (low-traffic geometry). M = 800 positions
// (50 exact 16-tiles), N = 16 co, K = 152 (150 + 2 pad).
// k-mapping k = 4m + c (2-way bank-benign). soff[152] LDS table
// (tile-invariant patch offsets; pad k>=150 -> 0, weight exactly 0).
// ILP-2 chains/tile. Weights f32 staged coalesced. LDS-bounce 512B stores.
// D-side mapping PROBED at runtime (r13-verified).
__global__ __launch_bounds__(512) void kconv2(const __hip_bfloat16* __restrict__ p1,
        const float* __restrict__ qw2t, __hip_bfloat16* __restrict__ c2,
        double* __restrict__ st2) {
    __shared__ float sxf[9408];        // 8 x [6][14][14] f32 (exact grid vals)
    __shared__ float swf[2432];        // [152][16] f32 weights, k-major (exact)
    __shared__ int soff[152];          // k -> x-tile offset (tile-invariant)
    __shared__ unsigned short sep[8][256];  // per-wave 16x16 bf16 out tile
    __shared__ double sred[16][2];
    int t = threadIdx.x;
    int b0 = blockIdx.x * 8;
    // stage x: 9408 bf16 -> f32, vectorized ushort4 (8B, coalesced)
    const ushort4* srcp = (const ushort4*)(p1 + (size_t)b0 * 1176);
    for (int i = t; i < 2352; i += 512) {
        ushort4 u = srcp[i];
        float* d = &sxf[4 * i];
        d[0] = bfval(u.x);
        d[1] = bfval(u.y);
        d[2] = bfval(u.z);
        d[3] = bfval(u.w);
    }
    // stage weights: pure coalesced copy (608 x float4, L2-resident)
    {
        const float4* wsrc = (const float4*)qw2t;
        float4* wdst = (float4*)swf;
        for (int i = t; i < 608; i += 512) wdst[i] = wsrc[i];
    }
    if (t < 152)
        soff[t] = (t < 150) ? (t / 25) * 196 + ((t % 25) / 5) * 14 + (t % 5) : 0;
    if (t < 32) ((double*)sred)[t] = 0.0;
    __syncthreads();

    int l = t & 63, w = t >> 6;        // lane, wave (0..7)
    int c = l >> 4, r16 = l & 15;      // k-group / {A-row,B-col} staging index

    // ---- layout probes (exact small-int arithmetic, 2 MFMAs) ----
    d4 pz = {0.0, 0.0, 0.0, 0.0};
    d4 prow = __builtin_amdgcn_mfma_f64_16x16x4f64((double)r16, 0.25, pz, 0, 0, 0);
    d4 pcol = __builtin_amdgcn_mfma_f64_16x16x4f64(1.0, 0.25 * (double)r16, pz, 0, 0, 0);
    int rowidx[4], colidx[4];
    #pragma unroll
    for (int j = 0; j < 4; ++j) { rowidx[j] = (int)prow[j]; colidx[j] = (int)pcol[j]; }

    unsigned short* myep = sep[w];
    double ls = 0.0, ls2 = 0.0;        // per-lane stats (col fixed per lane)
    int co0 = colidx[0];
    for (int tile = w; tile < 50; tile += 8) {
        int pos = tile * 16 + r16;     // A-row (staging) for this lane
        int abase = (pos / 100) * 1176 + ((pos % 100) / 10) * 14 + (pos % 10);
        d4 a0 = {0.0, 0.0, 0.0, 0.0}, a1 = {0.0, 0.0, 0.0, 0.0};
        #pragma unroll
        for (int s = 0; s < 19; ++s) {
            int k0 = 4 * s + c;              // chain 0: m = s
            int k1 = 4 * (s + 19) + c;       // chain 1: m = s + 19
            // pad slots (k>=150) have soff 0 and weight exactly 0 -> 0.
            double x0 = (double)sxf[abase + soff[k0]];
            double x1 = (double)sxf[abase + soff[k1]];
            double w0 = (double)swf[k0 * 16 + r16];
            double w1 = (double)swf[k1 * 16 + r16];
            a0 = __builtin_amdgcn_mfma_f64_16x16x4f64(x0, w0, a0, 0, 0, 0);
            a1 = __builtin_amdgcn_mfma_f64_16x16x4f64(x1, w1, a1, 0, 0, 0);
        }
        // epilogue: fq + stats; assemble tile in LDS (probed mapping), then
        // ONE coalesced 512B wave store (c2 tile region is contiguous).
        #pragma unroll
        for (int j = 0; j < 4; ++j) {
            double q = fq_d(a0[j] + a1[j]);
            myep[rowidx[j] * 16 + colidx[j]] = bfbits(q);
            ls += q; ls2 += q * q;
        }
        ushort4 v = *(const ushort4*)&myep[l * 4];   // wave-internal, in-order
        *(ushort4*)((unsigned short*)c2 + ((size_t)b0 * 100 + tile * 16) * 16 + l * 4) = v;
    }
    atomicAdd(&sred[co0][0], ls);
    atomicAdd(&sred[co0][1], ls2);
    __syncthreads();
    if (t < 32) atomicAdd(&st2[t * 32 + (blockIdx.x & 31)], ((double*)sred)[t]);
}

// ---------------- fc1: fused bn2-finalize + bn2/fq/relu/pool staging -------
// BT=8 (1024 blocks): c2 [B,100,16] position-major. Pool reads global
// directly with c-fastest map: 16 consecutive channels per 16-thread
// cluster -> 32B-contiguous loads. LDS 25.9KB -> 6 blocks/CU.
__global__ __launch_bounds__(256) void kfc1(const __hip_bfloat16* __restrict__ c2,
        const double* __restrict__ st2, const float* __restrict__ g2,
        const float* __restrict__ be2, const float* __restrict__ Wt,
        const float* __restrict__ qb, __hip_bfloat16* __restrict__ outb) {
    constexpr int IN = 400, OUT = 120, OUTP = 128, ROWS = 4, BT = 8;
    __shared__ double sx[BT][IN];
    __shared__ double sbn[16][4];
    int t = threadIdx.x;
    int b0 = blockIdx.x * BT;
    if (t < 16) {                       // inline bn2 finalize from stat bins
        double s = 0.0, s2 = 0.0;
        for (int b = 0; b < 32; ++b) { s += st2[t * 64 + b]; s2 += st2[t * 64 + 32 + b]; }
        double m = s / (819200.0);      // 8192*100
        double v = s2 / (819200.0) - m * m;
        sbn[t][0] = m; sbn[t][1] = 1.0 / sqrt(v + 1e-5);
        sbn[t][2] = (double)g2[t]; sbn[t][3] = (double)be2[t];
    }
    __syncthreads();
    for (int i = t; i < BT * IN; i += 256) {
        int cc = i & 15;                // channel fastest (coalesced)
        int rem = (i >> 4) % 25;        // pooled position
        int r = i / 400;                // image row within tile
        int ph = rem / 5, pw = rem % 5;
        const __hip_bfloat16* src = c2 + ((size_t)(b0 + r) * 100 + 20 * ph + 2 * pw) * 16 + cc;
        double m = sbn[cc][0], rr = sbn[cc][1], gg = sbn[cc][2], bb = sbn[cc][3];
        float f0 = __bfloat162float(src[0]),   f1 = __bfloat162float(src[16]);
        float f2 = __bfloat162float(src[160]), f3 = __bfloat162float(src[176]);
        bool useMax = (rr * gg) >= 0.0;
        float v = useMax ? fmaxf(fmaxf(f0, f1), fmaxf(f2, f3))
                         : fminf(fminf(f0, f1), fminf(f2, f3));
        double q = fq_d((((double)v - m) * rr) * gg + bb);
        sx[r][cc * 25 + rem] = fmax(q, 0.0);
    }
    __syncthreads();
    int o = t % OUTP;
    int g = t / OUTP;
    double acc[ROWS];
    double bias = (o < OUT) ? (double)qb[o] : 0.0;
    #pragma unroll
    for (int r = 0; r < ROWS; ++r) acc[r] = bias;
    #pragma unroll 4
    for (int k = 0; k < IN; ++k) {
        double w = (double)Wt[k * OUTP + o];   // coalesced, L2-resident
        #pragma unroll
        for (int r = 0; r < ROWS; ++r)
            acc[r] = fma(sx[g * ROWS + r][k], w, acc[r]);
    }
    if (o < OUT) {
        #pragma unroll
        for (int r = 0; r < ROWS; ++r) {
            double q = fq_d(acc[r]);
            if (q < 0.0) q = 0.0;
            outb[(size_t)(b0 + g * ROWS + r) * OUT + o] = __float2bfloat16((float)q);
        }
    }
}

// ---------------- fused fc2+fc3: a1 [B,120] -> out [B,10] ----------------
__global__ __launch_bounds__(256) void kfc23(const __hip_bfloat16* __restrict__ a1,
        const float* __restrict__ Wt2, const float* __restrict__ qfb2,
        const float* __restrict__ Wt3, const float* __restrict__ qfb3,
        float* __restrict__ out) {
    __shared__ double sx1[16][120];
    __shared__ double s2[16][84];
    int t = threadIdx.x;
    int b0 = blockIdx.x * 16;
    for (int i = t; i < 16 * 120; i += 256) {
        int r = i / 120, k = i % 120;
        sx1[r][k] = (double)__bfloat162float(a1[(size_t)(b0 + r) * 120 + k]);
    }
    __syncthreads();
    {   // fc2: 2 groups x 8 rows x 128 output lanes
        int o = t % 128, g = t / 128;
        double acc[8];
        double bias = (o < 84) ? (double)qfb2[o] : 0.0;
        #pragma unroll
        for (int r = 0; r < 8; ++r) acc[r] = bias;
        #pragma unroll 4
        for (int k = 0; k < 120; ++k) {
            double w = (double)Wt2[k * 128 + o];
            #pragma unroll
            for (int r = 0; r < 8; ++r)
                acc[r] = fma(sx1[g * 8 + r][k], w, acc[r]);
        }
        if (o < 84) {
            #pragma unroll
            for (int r = 0; r < 8; ++r) {
                double q = fq_d(acc[r]);
                s2[g * 8 + r][o] = fmax(q, 0.0);
            }
        }
    }
    __syncthreads();
    {   // fc3: 16 rows x 16 output lanes (10 used)
        int o = t % 16, g = t / 16;
        double acc = (o < 10) ? (double)qfb3[o] : 0.0;
        #pragma unroll 4
        for (int k = 0; k < 84; ++k)
            acc = fma(s2[g][k], (double)Wt3[k * 16 + o], acc);
        if (o < 10)
            out[(size_t)(b0 + g) * 10 + o] = (float)fq_d(acc);
    }
}

// ---------------------------------------------------------------------------
extern "C" void kernel_launch(void* const* d_in, const int* in_sizes, int n_in,
                              void* d_out, int out_size, void* d_ws, size_t ws_size,
                              hipStream_t stream) {
    const float* x   = (const float*)d_in[0];
    const float* w1  = (const float*)d_in[1];
    const float* g1  = (const float*)d_in[2];
    const float* be1 = (const float*)d_in[3];
    const float* w2  = (const float*)d_in[4];
    const float* g2  = (const float*)d_in[5];
    const float* be2 = (const float*)d_in[6];
    const float* fw1 = (const float*)d_in[7];
    const float* fb1 = (const float*)d_in[8];
    const float* fw2 = (const float*)d_in[9];
    const float* fb2 = (const float*)d_in[10];
    const float* fw3 = (const float*)d_in[11];
    const float* fb3 = (const float*)d_in[12];

    char* ws = (char*)d_ws;
    double* stats1 = (double*)(ws + 0);      // [6][2][32] dbl
    double* stats2 = (double*)(ws + 3072);   // [16][2][32] dbl (ends 11264)
    double* mr1    = (double*)(ws + 11264);  // 12 dbl
    float* qw1  = (float*)(ws + 12288);
    float* qw2t = (float*)(ws + 13312);      // [152][16] f32, ends 23040
    float* qfb1 = (float*)(ws + 23040);
    float* qfb2 = (float*)(ws + 23552);
    float* qfb3 = (float*)(ws + 24064);
    float* Wt1  = (float*)(ws + 24576);      // 400*128
    float* Wt2  = (float*)(ws + 229376);     // 120*128
    float* Wt3  = (float*)(ws + 290816);     // 84*16
    unsigned short* praw = (unsigned short*)(ws + 303104);    // [B,6,14,14] 19.3 MB
    __hip_bfloat16* p1 = (__hip_bfloat16*)(ws + 77373440);    // [B,6,14,14] 19.3 MB
    __hip_bfloat16* c2 = (__hip_bfloat16*)(ws + 303104);      // [B,100,16] (praw dead)
    __hip_bfloat16* a1 = (__hip_bfloat16*)(ws + 303104 + 26214400); // [B,120]

    hipMemsetAsync(ws, 0, 11264, stream);

    kprep<<<(PREP_TOTAL + 255) / 256, 256, 0, stream>>>(
        w1, w2, fb1, fb2, fb3, fw1, fw2, fw3,
        qw1, qw2t, qfb1, qfb2, qfb3, Wt1, Wt2, Wt3);

    // conv1 + fq + stats + inline pool -> praw  (3 images/block, 2x14 tiles)
    kconv1<<<(BATCH + 2) / 3, 512, 0, stream>>>(x, qw1, g1, praw, BATCH, stats1);
    kfinal<<<1, 32, 0, stream>>>(stats1, mr1, 6, (double)BATCH * 784.0);
    // bn1 + fq + relu on pooled values -> p1 (elementwise, ushort4)
    kbn1<<<BATCH * 6 * 49 / 256, 256, 0, stream>>>(praw, mr1, g1, be1, p1);
    // conv2 via f64 MFMA implicit GEMM (soff table, 8-wave blocks) -> c2
    kconv2<<<BATCH / 8, 512, 0, stream>>>(p1, qw2t, c2, stats2);
    // fc1 (inline bn2 finalize + fused pool staging, +relu) -> a1 [B,120]
    kfc1<<<BATCH / 8, 256, 0, stream>>>(c2, stats2, g2, be2, Wt1, qfb1, a1);
    // fused fc2+fc3 -> d_out [B,10] float
    kfc23<<<BATCH / 16, 256, 0, stream>>>(a1, Wt2, qfb2, Wt3, qfb3, (float*)d_out);
}

// Round 12
// 373.586 us; speedup vs baseline: 1.0799x; 1.0127x over previous
//
#include <hip/hip_runtime.h>
#include <hip/hip_bf16.h>

// ---------------------------------------------------------------------------
// QLenet forward, exact-math strategy:
//   All fq() outputs are e5m2 grid values (<=3 significant bits). Products of
//   two grid values have <=6-bit mantissas; dot sums (<=400 terms, bounded
//   exponent span) are EXACT in f64 -> order-independent -> matches float64
//   numpy reference. Intermediates stored as bf16 (exact for grid values);
//   LDS tiles hold f32 (exact), accumulation stays f64.
// Round 22 -> 23:
//   * r22: pool-fusion WIN (378us best; kconv1 WRITE 76->20MB, 132->119us).
//     Tail analysis: ~150us in 7 launches; kbn1+kfinal exist only to apply
//     BN1 before kconv2 reads p1.
//   * r23a: BN1 (+stats finalize) fused into kconv2's staging loop (reads
//     praw directly, same expression as kbn1 verbatim). kbn1+kfinal launches
//     removed; 38.6MB HBM round-trip removed. praw/c2 un-aliased.
//   * r23b: kconv2 ILP-4 (chains 10/10/9/9): MfmaUtil ~48% @ ILP-2 x
//     2 waves/SIMD suggests f64 MFMA dep latency (~140cy vs 64cy issue)
//     still exposed. +16 VGPR. Partial sums exact under any association.
// ---------------------------------------------------------------------------

#define BATCH 8192

typedef double d4 __attribute__((ext_vector_type(4)));

// fq on f64: round to FP(e5m2) nearest-even, subnormal granule 2^-16,
// clip +-57344. Integer RNE on the mantissa; carry propagates into exponent.
__device__ __forceinline__ double fq_d(double x) {
    long long b = __double_as_longlong(x);
    long long ab = b & 0x7fffffffffffffffLL;
    if (ab == 0) return x;                       // +-0 preserved
    double q;
    if (ab >= 0x3F10000000000000LL) {            // |x| >= 2^-14
        long long r = b + 0x0001FFFFFFFFFFFFLL + ((b >> 50) & 1LL);
        r &= 0xFFFC000000000000LL;
        q = __longlong_as_double(r);
        q = fmin(fmax(q, -57344.0), 57344.0);
    } else {                                     // subnormal grid: 2^-16
        q = rint(x * 65536.0) * 1.52587890625e-05;
    }
    return q;
}

// fq on f32 input values (exact f32 -> same e5m2 result as the f64 path).
__device__ __forceinline__ float fq_f(float x) {
    int b = __float_as_int(x);
    int ab = b & 0x7fffffff;
    if (ab == 0) return x;
    float q;
    if (ab >= 0x38800000) {                      // |x| >= 2^-14
        int r = b + 0x000FFFFF + ((b >> 21) & 1);
        r &= 0xFFE00000;                         // sign+exp+2 mantissa bits
        q = __int_as_float(r);
        q = fminf(fmaxf(q, -57344.0f), 57344.0f);
    } else {
        q = rintf(x * 65536.0f) * 1.52587890625e-05f;
    }
    return q;
}

__device__ __forceinline__ unsigned short bfbits(double q) {
    __hip_bfloat16 h = __float2bfloat16((float)q);   // exact for grid values
    return *(unsigned short*)&h;
}

__device__ __forceinline__ float bfval(unsigned short u) {
    return __bfloat162float(*(__hip_bfloat16*)&u);
}

// ---------------- merged prep (all f32-path fq) ----------------
// qw2t: conv2 weights pre-transposed to [152][16] f32 (k-major, zero-padded)
// so kconv2's LDS staging is a pure coalesced copy.
__global__ void kprep(const float* __restrict__ w1, const float* __restrict__ w2,
                      const float* __restrict__ fb1, const float* __restrict__ fb2,
                      const float* __restrict__ fb3, const float* __restrict__ fw1,
                      const float* __restrict__ fw2, const float* __restrict__ fw3,
                      float* __restrict__ qw1, float* __restrict__ qw2t,
                      float* __restrict__ qfb1, float* __restrict__ qfb2,
                      float* __restrict__ qfb3, float* __restrict__ Wt1,
                      float* __restrict__ Wt2, float* __restrict__ Wt3) {
    int i = blockIdx.x * 256 + threadIdx.x;
    if (i < 150) { qw1[i] = fq_f(w1[i]); return; }
    i -= 150;
    if (i < 2432) { int k = i >> 4, co = i & 15;
        qw2t[i] = (k < 150) ? fq_f(w2[co * 150 + k]) : 0.0f; return; }
    i -= 2432;
    if (i < 120) { qfb1[i] = fq_f(fb1[i]); return; }
    i -= 120;
    if (i < 84) { qfb2[i] = fq_f(fb2[i]); return; }
    i -= 84;
    if (i < 10) { qfb3[i] = fq_f(fb3[i]); return; }
    i -= 10;
    if (i < 51200) { int k = i / 128, o = i % 128;
        Wt1[i] = (o < 120) ? fq_f(fw1[o * 400 + k]) : 0.0f; return; }
    i -= 51200;
    if (i < 15360) { int k = i / 128, o = i % 128;
        Wt2[i] = (o < 84) ? fq_f(fw2[o * 120 + k]) : 0.0f; return; }
    i -= 15360;
    if (i < 1344) { int k = i / 16, o = i % 16;
        Wt3[i] = (o < 10) ? fq_f(fw3[o * 84 + k]) : 0.0f; return; }
}
#define PREP_TOTAL (150 + 2432 + 120 + 84 + 10 + 51200 + 15360 + 1344)

// ---------------- conv1 + fq + stats + inline 2x2 pool ----------------
// [B,1,32,32] -> praw [B,6,14,14] (pooled raw max-or-min of fq'd conv out).
// 3 images/block, 512 thr; task = (img, co, rowpair, half) = 2x14 tile ->
// 7 complete pool windows; 504 tasks -> one task/thread. Selection uses
// sign(g1[co]) only (r>0 always; fq/relu/bn monotone) — no stats needed.
__global__ __launch_bounds__(512) void kconv1(const float* __restrict__ x,
        const float* __restrict__ qw, const float* __restrict__ g1,
        unsigned short* __restrict__ praw, int nimg_total,
        double* __restrict__ st1) {
    __shared__ float sxf[3 * 1056];   // 3 x (32 rows x 33) f32 (12.7 KB)
    __shared__ double swd[152];
    __shared__ float sg1[6];
    __shared__ double sred[6][2];
    int t = threadIdx.x;
    int b0 = blockIdx.x * 3;
    int nimg = nimg_total - b0; if (nimg > 3) nimg = 3;
    for (int i = t; i < nimg * 1024; i += 512) {
        int img = i >> 10, idx = i & 1023;
        sxf[img * 1056 + (idx >> 5) * 33 + (idx & 31)] =
            fq_f(x[(size_t)(b0 + img) * 1024 + idx]);
    }
    if (t < 150) swd[t] = (double)qw[t];
    if (t >= 160 && t < 166) sg1[t - 160] = g1[t - 160];
    if (t >= 192 && t < 204) ((double*)sred)[t - 192] = 0.0;
    __syncthreads();
    int ntask = nimg * 168;           // 6 co x 14 rowpairs x 2 halves
    for (int task = t; task < ntask; task += 512) {
        int img = task / 168; int rr = task % 168;
        int co = rr / 28; int rem = rr % 28;
        int ph = rem >> 1;            // pooled row 0..13
        int half = rem & 1;           // col half 0/1
        int i0 = 2 * ph;              // c1 rows i0, i0+1
        int j0 = half * 14;           // c1 cols j0..j0+13
        const double* wp = &swd[co * 25];
        double a0[14], a1[14];
        #pragma unroll
        for (int j = 0; j < 14; ++j) { a0[j] = 0.0; a1[j] = 0.0; }
        double wr[5], wq[5];
        #pragma unroll
        for (int u = 0; u < 6; ++u) {
            const float* xr = &sxf[img * 1056 + (i0 + u) * 33 + j0];
            double xv[18];
            #pragma unroll
            for (int k = 0; k < 18; ++k) xv[k] = (double)xr[k];
            if (u < 5) {
                #pragma unroll
                for (int tt = 0; tt < 5; ++tt) wr[tt] = wp[u * 5 + tt];
                #pragma unroll
                for (int j = 0; j < 14; ++j)
                    a0[j] = fma(xv[j], wr[0], fma(xv[j+1], wr[1], fma(xv[j+2], wr[2],
                            fma(xv[j+3], wr[3], fma(xv[j+4], wr[4], a0[j])))));
            }
            if (u >= 1) {
                #pragma unroll
                for (int j = 0; j < 14; ++j)
                    a1[j] = fma(xv[j], wq[0], fma(xv[j+1], wq[1], fma(xv[j+2], wq[2],
                            fma(xv[j+3], wq[3], fma(xv[j+4], wq[4], a1[j])))));
            }
            #pragma unroll
            for (int tt = 0; tt < 5; ++tt) wq[tt] = wr[tt];   // SSA rotate
        }
        // epilogue: fq (needed for stats anyway) + stats + 2x2 pool of the
        // fq'd values (max if g1[co]>=0 else min; monotone chain) -> 7 vals.
        double q0[14], q1[14];
        double s = 0.0, s2 = 0.0;
        #pragma unroll
        for (int j = 0; j < 14; ++j) {
            q0[j] = fq_d(a0[j]); q1[j] = fq_d(a1[j]);
            s += q0[j] + q1[j]; s2 += q0[j] * q0[j] + q1[j] * q1[j];
        }
        bool useMax = (sg1[co] >= 0.0f);
        unsigned short* dst = praw + ((size_t)(b0 + img) * 6 + co) * 196 + ph * 14 + half * 7;
        #pragma unroll
        for (int jp = 0; jp < 7; ++jp) {
            double pmax = fmax(fmax(q0[2*jp], q0[2*jp+1]), fmax(q1[2*jp], q1[2*jp+1]));
            double pmin = fmin(fmin(q0[2*jp], q0[2*jp+1]), fmin(q1[2*jp], q1[2*jp+1]));
            dst[jp] = bfbits(useMax ? pmax : pmin);
        }
        atomicAdd(&sred[co][0], s);
        atomicAdd(&sred[co][1], s2);
    }
    __syncthreads();
    if (t < 12) atomicAdd(&st1[t * 32 + (blockIdx.x & 31)], ((double*)sred)[t]);
}

// ---------------- conv2 + fused BN1 staging, f64 MFMA implicit GEMM -------
// praw [B,6,14,14] -> c2 [B,100,16]. 8 images/block, 512 thr = 8 waves,
// grid 1024 (low-traffic geometry). M = 800 positions (50 exact 16-tiles),
// N = 16 co, K = 152 (150 + 2 pad).
// r23: BN1 finalize (from st1 bins) + bn/fq/relu applied inline during x
// staging (kbn1's expression verbatim) — kbn1/kfinal kernels removed.
// ILP-4 chains (10/10/9/9) to cover f64 MFMA dep latency.
// k-mapping k = 4m + c (2-way bank-benign); soff[152] LDS offset table;
// weights f32 staged coalesced; LDS-bounce 512B stores; D-side layout
// PROBED at runtime (r13-verified).
__global__ __launch_bounds__(512) void kconv2(const unsigned short* __restrict__ praw,
        const double* __restrict__ st1, const float* __restrict__ g1,
        const float* __restrict__ be1, const float* __restrict__ qw2t,
        __hip_bfloat16* __restrict__ c2, double* __restrict__ st2) {
    __shared__ float sxf[9408];        // 8 x [6][14][14] f32 (exact grid vals)
    __shared__ float swf[2432];        // [152][16] f32 weights, k-major (exact)
    __shared__ int soff[152];          // k -> x-tile offset (tile-invariant)
    __shared__ unsigned short sep[8][256];  // per-wave 16x16 bf16 out tile
    __shared__ double sred[16][2];
    __shared__ double sbn1[6][4];      // m, rsigma, gamma, beta
    int t = threadIdx.x;
    int b0 = blockIdx.x * 8;
    // weights: pure coalesced copy (608 x float4, L2-resident)
    {
        const float4* wsrc = (const float4*)qw2t;
        float4* wdst = (float4*)swf;
        for (int i = t; i < 608; i += 512) wdst[i] = wsrc[i];
    }
    if (t < 152)
        soff[t] = (t < 150) ? (t / 25) * 196 + ((t % 25) / 5) * 14 + (t % 5) : 0;
    if (t < 32) ((double*)sred)[t] = 0.0;
    if (t < 6) {                       // inline BN1 finalize from stat bins
        double s = 0.0, s2 = 0.0;
        for (int b = 0; b < 32; ++b) { s += st1[t * 64 + b]; s2 += st1[t * 64 + 32 + b]; }
        double m = s / 6422528.0;      // 8192*784
        double v = s2 / 6422528.0 - m * m;
        sbn1[t][0] = m; sbn1[t][1] = 1.0 / sqrt(v + 1e-5);
        sbn1[t][2] = (double)g1[t]; sbn1[t][3] = (double)be1[t];
    }
    __syncthreads();
    // stage x: praw bf16 -> bn1+fq+relu -> f32 (kbn1's math, fused here).
    // 4-elem groups never cross channel boundaries (196 = 4*49).
    const ushort4* srcp = (const ushort4*)(praw + (size_t)b0 * 1176);
    for (int i = t; i < 2352; i += 512) {
        ushort4 u = srcp[i];
        int ch = ((4 * i) % 1176) / 196;
        double m = sbn1[ch][0], r = sbn1[ch][1];
        double gg = sbn1[ch][2], bb = sbn1[ch][3];
        float* d = &sxf[4 * i];
        double q;
        q = fq_d((((double)bfval(u.x) - m) * r) * gg + bb); d[0] = (float)fmax(q, 0.0);
        q = fq_d((((double)bfval(u.y) - m) * r) * gg + bb); d[1] = (float)fmax(q, 0.0);
        q = fq_d((((double)bfval(u.z) - m) * r) * gg + bb); d[2] = (float)fmax(q, 0.0);
        q = fq_d((((double)bfval(u.w) - m) * r) * gg + bb); d[3] = (float)fmax(q, 0.0);
    }
    __syncthreads();

    int l = t & 63, w = t >> 6;        // lane, wave (0..7)
    int c = l >> 4, r16 = l & 15;      // k-group / {A-row,B-col} staging index

    // ---- layout probes (exact small-int arithmetic, 2 MFMAs) ----
    d4 pz = {0.0, 0.0, 0.0, 0.0};
    d4 prow = __builtin_amdgcn_mfma_f64_16x16x4f64((double)r16, 0.25, pz, 0, 0, 0);
    d4 pcol = __builtin_amdgcn_mfma_f64_16x16x4f64(1.0, 0.25 * (double)r16, pz, 0, 0, 0);
    int rowidx[4], colidx[4];
    #pragma unroll
    for (int j = 0; j < 4; ++j) { rowidx[j] = (int)prow[j]; colidx[j] = (int)pcol[j]; }

    unsigned short* myep = sep[w];
    double ls = 0.0, ls2 = 0.0;        // per-lane stats (col fixed per lane)
    int co0 = colidx[0];
    for (int tile = w; tile < 50; tile += 8) {
        int pos = tile * 16 + r16;     // A-row (staging) for this lane
        int abase = (pos / 100) * 1176 + ((pos % 100) / 10) * 14 + (pos % 10);
        d4 a0 = {0.0, 0.0, 0.0, 0.0}, a1 = {0.0, 0.0, 0.0, 0.0};
        d4 a2 = {0.0, 0.0, 0.0, 0.0}, a3 = {0.0, 0.0, 0.0, 0.0};
        #pragma unroll
        for (int s = 0; s < 10; ++s) {
            int k0 = 4 * s + c;                 // chain 0: m in [0,10)
            int k1 = 4 * (s + 10) + c;          // chain 1: m in [10,20)
            double x0 = (double)sxf[abase + soff[k0]];
            double w0 = (double)swf[k0 * 16 + r16];
            a0 = __builtin_amdgcn_mfma_f64_16x16x4f64(x0, w0, a0, 0, 0, 0);
            double x1 = (double)sxf[abase + soff[k1]];
            double w1 = (double)swf[k1 * 16 + r16];
            a1 = __builtin_amdgcn_mfma_f64_16x16x4f64(x1, w1, a1, 0, 0, 0);
            if (s < 9) {
                int k2 = 4 * (s + 20) + c;      // chain 2: m in [20,29)
                int k3 = 4 * (s + 29) + c;      // chain 3: m in [29,38)
                double x2 = (double)sxf[abase + soff[k2]];
                double w2 = (double)swf[k2 * 16 + r16];
                a2 = __builtin_amdgcn_mfma_f64_16x16x4f64(x2, w2, a2, 0, 0, 0);
                double x3 = (double)sxf[abase + soff[k3]];
                double w3 = (double)swf[k3 * 16 + r16];
                a3 = __builtin_amdgcn_mfma_f64_16x16x4f64(x3, w3, a3, 0, 0, 0);
            }
        }
        // epilogue: fq + stats; assemble tile in LDS (probed mapping), then
        // ONE coalesced 512B wave store (c2 tile region is contiguous).
        // (a0+a1)+(a2+a3): every partial sum exact -> association-free.
        #pragma unroll
        for (int j = 0; j < 4; ++j) {
            double q = fq_d((a0[j] + a1[j]) + (a2[j] + a3[j]));
            myep[rowidx[j] * 16 + colidx[j]] = bfbits(q);
            ls += q; ls2 += q * q;
        }
        ushort4 v = *(const ushort4*)&myep[l * 4];   // wave-internal, in-order
        *(ushort4*)((unsigned short*)c2 + ((size_t)b0 * 100 + tile * 16) * 16 + l * 4) = v;
    }
    atomicAdd(&sred[co0][0], ls);
    atomicAdd(&sred[co0][1], ls2);
    __syncthreads();
    if (t < 32) atomicAdd(&st2[t * 32 + (blockIdx.x & 31)], ((double*)sred)[t]);
}

// ---------------- fc1: fused bn2-finalize + bn2/fq/relu/pool staging -------
// BT=8 (1024 blocks): c2 [B,100,16] position-major. Pool reads global
// directly with c-fastest map: 16 consecutive channels per 16-thread
// cluster -> 32B-contiguous loads. LDS 25.9KB -> 6 blocks/CU.
__global__ __launch_bounds__(256) void kfc1(const __hip_bfloat16* __restrict__ c2,
        const double* __restrict__ st2, const float* __restrict__ g2,
        const float* __restrict__ be2, const float* __restrict__ Wt,
        const float* __restrict__ qb, __hip_bfloat16* __restrict__ outb) {
    constexpr int IN = 400, OUT = 120, OUTP = 128, ROWS = 4, BT = 8;
    __shared__ double sx[BT][IN];
    __shared__ double sbn[16][4];
    int t = threadIdx.x;
    int b0 = blockIdx.x * BT;
    if (t < 16) {                       // inline bn2 finalize from stat bins
        double s = 0.0, s2 = 0.0;
        for (int b = 0; b < 32; ++b) { s += st2[t * 64 + b]; s2 += st2[t * 64 + 32 + b]; }
        double m = s / (819200.0);      // 8192*100
        double v = s2 / (819200.0) - m * m;
        sbn[t][0] = m; sbn[t][1] = 1.0 / sqrt(v + 1e-5);
        sbn[t][2] = (double)g2[t]; sbn[t][3] = (double)be2[t];
    }
    __syncthreads();
    for (int i = t; i < BT * IN; i += 256) {
        int cc = i & 15;                // channel fastest (coalesced)
        int rem = (i >> 4) % 25;        // pooled position
        int r = i / 400;                // image row within tile
        int ph = rem / 5, pw = rem % 5;
        const __hip_bfloat16* src = c2 + ((size_t)(b0 + r) * 100 + 20 * ph + 2 * pw) * 16 + cc;
        double m = sbn[cc][0], rr = sbn[cc][1], gg = sbn[cc][2], bb = sbn[cc][3];
        float f0 = __bfloat162float(src[0]),   f1 = __bfloat162float(src[16]);
        float f2 = __bfloat162float(src[160]), f3 = __bfloat162float(src[176]);
        bool useMax = (rr * gg) >= 0.0;
        float v = useMax ? fmaxf(fmaxf(f0, f1), fmaxf(f2, f3))
                         : fminf(fminf(f0, f1), fminf(f2, f3));
        double q = fq_d((((double)v - m) * rr) * gg + bb);
        sx[r][cc * 25 + rem] = fmax(q, 0.0);
    }
    __syncthreads();
    int o = t % OUTP;
    int g = t / OUTP;
    double acc[ROWS];
    double bias = (o < OUT) ? (double)qb[o] : 0.0;
    #pragma unroll
    for (int r = 0; r < ROWS; ++r) acc[r] = bias;
    #pragma unroll 4
    for (int k = 0; k < IN; ++k) {
        double w = (double)Wt[k * OUTP + o];   // coalesced, L2-resident
        #pragma unroll
        for (int r = 0; r < ROWS; ++r)
            acc[r] = fma(sx[g * ROWS + r][k], w, acc[r]);
    }
    if (o < OUT) {
        #pragma unroll
        for (int r = 0; r < ROWS; ++r) {
            double q = fq_d(acc[r]);
            if (q < 0.0) q = 0.0;
            outb[(size_t)(b0 + g * ROWS + r) * OUT + o] = __float2bfloat16((float)q);
        }
    }
}

// ---------------- fused fc2+fc3: a1 [B,120] -> out [B,10] ----------------
__global__ __launch_bounds__(256) void kfc23(const __hip_bfloat16* __restrict__ a1,
        const float* __restrict__ Wt2, const float* __restrict__ qfb2,
        const float* __restrict__ Wt3, const float* __restrict__ qfb3,
        float* __restrict__ out) {
    __shared__ double sx1[16][120];
    __shared__ double s2[16][84];
    int t = threadIdx.x;
    int b0 = blockIdx.x * 16;
    for (int i = t; i < 16 * 120; i += 256) {
        int r = i / 120, k = i % 120;
        sx1[r][k] = (double)__bfloat162float(a1[(size_t)(b0 + r) * 120 + k]);
    }
    __syncthreads();
    {   // fc2: 2 groups x 8 rows x 128 output lanes
        int o = t % 128, g = t / 128;
        double acc[8];
        double bias = (o < 84) ? (double)qfb2[o] : 0.0;
        #pragma unroll
        for (int r = 0; r < 8; ++r) acc[r] = bias;
        #pragma unroll 4
        for (int k = 0; k < 120; ++k) {
            double w = (double)Wt2[k * 128 + o];
            #pragma unroll
            for (int r = 0; r < 8; ++r)
                acc[r] = fma(sx1[g * 8 + r][k], w, acc[r]);
        }
        if (o < 84) {
            #pragma unroll
            for (int r = 0; r < 8; ++r) {
                double q = fq_d(acc[r]);
                s2[g * 8 + r][o] = fmax(q, 0.0);
            }
        }
    }
    __syncthreads();
    {   // fc3: 16 rows x 16 output lanes (10 used)
        int o = t % 16, g = t / 16;
        double acc = (o < 10) ? (double)qfb3[o] : 0.0;
        #pragma unroll 4
        for (int k = 0; k < 84; ++k)
            acc = fma(s2[g][k], (double)Wt3[k * 16 + o], acc);
        if (o < 10)
            out[(size_t)(b0 + g) * 10 + o] = (float)fq_d(acc);
    }
}

// ---------------------------------------------------------------------------
extern "C" void kernel_launch(void* const* d_in, const int* in_sizes, int n_in,
                              void* d_out, int out_size, void* d_ws, size_t ws_size,
                              hipStream_t stream) {
    const float* x   = (const float*)d_in[0];
    const float* w1  = (const float*)d_in[1];
    const float* g1  = (const float*)d_in[2];
    const float* be1 = (const float*)d_in[3];
    const float* w2  = (const float*)d_in[4];
    const float* g2  = (const float*)d_in[5];
    const float* be2 = (const float*)d_in[6];
    const float* fw1 = (const float*)d_in[7];
    const float* fb1 = (const float*)d_in[8];
    const float* fw2 = (const float*)d_in[9];
    const float* fb2 = (const float*)d_in[10];
    const float* fw3 = (const float*)d_in[11];
    const float* fb3 = (const float*)d_in[12];

    char* ws = (char*)d_ws;
    double* stats1 = (double*)(ws + 0);      // [6][2][32] dbl
    double* stats2 = (double*)(ws + 3072);   // [16][2][32] dbl (ends 11264)
    float* qw1  = (float*)(ws + 12288);
    float* qw2t = (float*)(ws + 13312);      // [152][16] f32, ends 23040
    float* qfb1 = (float*)(ws + 23040);
    float* qfb2 = (float*)(ws + 23552);
    float* qfb3 = (float*)(ws + 24064);
    float* Wt1  = (float*)(ws + 24576);      // 400*128
    float* Wt2  = (float*)(ws + 229376);     // 120*128
    float* Wt3  = (float*)(ws + 290816);     // 84*16
    unsigned short* praw = (unsigned short*)(ws + 303104);        // [B,6,14,14] 19.3 MB
    __hip_bfloat16* c2 = (__hip_bfloat16*)(ws + 19570688);        // [B,100,16] 26.2 MB
    __hip_bfloat16* a1 = (__hip_bfloat16*)(ws + 45785088);        // [B,120] 2 MB

    hipMemsetAsync(ws, 0, 11264, stream);

    kprep<<<(PREP_TOTAL + 255) / 256, 256, 0, stream>>>(
        w1, w2, fb1, fb2, fb3, fw1, fw2, fw3,
        qw1, qw2t, qfb1, qfb2, qfb3, Wt1, Wt2, Wt3);

    // conv1 + fq + stats + inline pool -> praw  (3 images/block, 2x14 tiles)
    kconv1<<<(BATCH + 2) / 3, 512, 0, stream>>>(x, qw1, g1, praw, BATCH, stats1);
    // conv2 (fused BN1 finalize + bn/fq/relu staging; ILP-4 MFMA) -> c2
    kconv2<<<BATCH / 8, 512, 0, stream>>>(praw, stats1, g1, be1, qw2t, c2, stats2);
    // fc1 (inline bn2 finalize + fused pool staging, +relu) -> a1 [B,120]
    kfc1<<<BATCH / 8, 256, 0, stream>>>(c2, stats2, g2, be2, Wt1, qfb1, a1);
    // fused fc2+fc3 -> d_out [B,10] float
    kfc23<<<BATCH / 16, 256, 0, stream>>>(a1, Wt2, qfb2, Wt3, qfb3, (float*)d_out);
}

// Round 13
// 370.892 us; speedup vs baseline: 1.0877x; 1.0073x over previous
//
#include <hip/hip_runtime.h>
#include <hip/hip_bf16.h>

// ---------------------------------------------------------------------------
// QLenet forward, exact-math strategy:
//   All fq() outputs are e5m2 grid values (<=3 significant bits). Products of
//   two grid values have <=6-bit mantissas; dot sums (<=400 terms, bounded
//   exponent span) are EXACT in f64 -> order-independent -> matches float64
//   numpy reference. Intermediates stored as bf16 (exact for grid values);
//   LDS tiles hold f32 (exact), accumulation stays f64.
// Round 23 -> 24:
//   * r23 = 373.6us; kconv1 119-134 (run noise +-10%), kconv2 ~100,
//     kfc1+kfc23 ~100 combined, gaps/prep ~30.
//   * r24a: kfc1+kfc23 FUSED (kfc): the kfc1 block already holds its 8 rows'
//     full fc1 output -> fc2+fc3 run from LDS in-block. -1 launch, -a1
//     round trip, -kfc23 staging. LDS 39.2KB.
//   * r24b: kconv1 co-major task order (task = co*84+r): waves mostly
//     co-uniform -> swd weight reads become LDS broadcasts (were 2-3-way
//     splits), stats atomics less contended.
// ---------------------------------------------------------------------------

#define BATCH 8192

typedef double d4 __attribute__((ext_vector_type(4)));

// fq on f64: round to FP(e5m2) nearest-even, subnormal granule 2^-16,
// clip +-57344. Integer RNE on the mantissa; carry propagates into exponent.
__device__ __forceinline__ double fq_d(double x) {
    long long b = __double_as_longlong(x);
    long long ab = b & 0x7fffffffffffffffLL;
    if (ab == 0) return x;                       // +-0 preserved
    double q;
    if (ab >= 0x3F10000000000000LL) {            // |x| >= 2^-14
        long long r = b + 0x0001FFFFFFFFFFFFLL + ((b >> 50) & 1LL);
        r &= 0xFFFC000000000000LL;
        q = __longlong_as_double(r);
        q = fmin(fmax(q, -57344.0), 57344.0);
    } else {                                     // subnormal grid: 2^-16
        q = rint(x * 65536.0) * 1.52587890625e-05;
    }
    return q;
}

// fq on f32 input values (exact f32 -> same e5m2 result as the f64 path).
__device__ __forceinline__ float fq_f(float x) {
    int b = __float_as_int(x);
    int ab = b & 0x7fffffff;
    if (ab == 0) return x;
    float q;
    if (ab >= 0x38800000) {                      // |x| >= 2^-14
        int r = b + 0x000FFFFF + ((b >> 21) & 1);
        r &= 0xFFE00000;                         // sign+exp+2 mantissa bits
        q = __int_as_float(r);
        q = fminf(fmaxf(q, -57344.0f), 57344.0f);
    } else {
        q = rintf(x * 65536.0f) * 1.52587890625e-05f;
    }
    return q;
}

__device__ __forceinline__ unsigned short bfbits(double q) {
    __hip_bfloat16 h = __float2bfloat16((float)q);   // exact for grid values
    return *(unsigned short*)&h;
}

__device__ __forceinline__ float bfval(unsigned short u) {
    return __bfloat162float(*(__hip_bfloat16*)&u);
}

// ---------------- merged prep (all f32-path fq) ----------------
// qw2t: conv2 weights pre-transposed to [152][16] f32 (k-major, zero-padded)
// so kconv2's LDS staging is a pure coalesced copy.
__global__ void kprep(const float* __restrict__ w1, const float* __restrict__ w2,
                      const float* __restrict__ fb1, const float* __restrict__ fb2,
                      const float* __restrict__ fb3, const float* __restrict__ fw1,
                      const float* __restrict__ fw2, const float* __restrict__ fw3,
                      float* __restrict__ qw1, float* __restrict__ qw2t,
                      float* __restrict__ qfb1, float* __restrict__ qfb2,
                      float* __restrict__ qfb3, float* __restrict__ Wt1,
                      float* __restrict__ Wt2, float* __restrict__ Wt3) {
    int i = blockIdx.x * 256 + threadIdx.x;
    if (i < 150) { qw1[i] = fq_f(w1[i]); return; }
    i -= 150;
    if (i < 2432) { int k = i >> 4, co = i & 15;
        qw2t[i] = (k < 150) ? fq_f(w2[co * 150 + k]) : 0.0f; return; }
    i -= 2432;
    if (i < 120) { qfb1[i] = fq_f(fb1[i]); return; }
    i -= 120;
    if (i < 84) { qfb2[i] = fq_f(fb2[i]); return; }
    i -= 84;
    if (i < 10) { qfb3[i] = fq_f(fb3[i]); return; }
    i -= 10;
    if (i < 51200) { int k = i / 128, o = i % 128;
        Wt1[i] = (o < 120) ? fq_f(fw1[o * 400 + k]) : 0.0f; return; }
    i -= 51200;
    if (i < 15360) { int k = i / 128, o = i % 128;
        Wt2[i] = (o < 84) ? fq_f(fw2[o * 120 + k]) : 0.0f; return; }
    i -= 15360;
    if (i < 1344) { int k = i / 16, o = i % 16;
        Wt3[i] = (o < 10) ? fq_f(fw3[o * 84 + k]) : 0.0f; return; }
}
#define PREP_TOTAL (150 + 2432 + 120 + 84 + 10 + 51200 + 15360 + 1344)

// ---------------- conv1 + fq + stats + inline 2x2 pool ----------------
// [B,1,32,32] -> praw [B,6,14,14] (pooled raw max-or-min of fq'd conv out).
// 3 images/block, 512 thr; task = co*(nimg*28) + img*28 + (ph*2+half):
// co-major order -> waves mostly co-uniform (swd reads broadcast).
// Selection uses sign(g1[co]) only (r>0; fq/relu/bn monotone).
__global__ __launch_bounds__(512) void kconv1(const float* __restrict__ x,
        const float* __restrict__ qw, const float* __restrict__ g1,
        unsigned short* __restrict__ praw, int nimg_total,
        double* __restrict__ st1) {
    __shared__ float sxf[3 * 1056];   // 3 x (32 rows x 33) f32 (12.7 KB)
    __shared__ double swd[152];
    __shared__ float sg1[6];
    __shared__ double sred[6][2];
    int t = threadIdx.x;
    int b0 = blockIdx.x * 3;
    int nimg = nimg_total - b0; if (nimg > 3) nimg = 3;
    for (int i = t; i < nimg * 1024; i += 512) {
        int img = i >> 10, idx = i & 1023;
        sxf[img * 1056 + (idx >> 5) * 33 + (idx & 31)] =
            fq_f(x[(size_t)(b0 + img) * 1024 + idx]);
    }
    if (t < 150) swd[t] = (double)qw[t];
    if (t >= 160 && t < 166) sg1[t - 160] = g1[t - 160];
    if (t >= 192 && t < 204) ((double*)sred)[t - 192] = 0.0;
    __syncthreads();
    int M = nimg * 28;                // tasks per co
    int ntask = 6 * M;
    for (int task = t; task < ntask; task += 512) {
        int co = task / M; int r = task % M;
        int img = r / 28; int rem = r % 28;
        int ph = rem >> 1;            // pooled row 0..13
        int half = rem & 1;           // col half 0/1
        int i0 = 2 * ph;              // c1 rows i0, i0+1
        int j0 = half * 14;           // c1 cols j0..j0+13
        const double* wp = &swd[co * 25];
        double a0[14], a1[14];
        #pragma unroll
        for (int j = 0; j < 14; ++j) { a0[j] = 0.0; a1[j] = 0.0; }
        double wr[5], wq[5];
        #pragma unroll
        for (int u = 0; u < 6; ++u) {
            const float* xr = &sxf[img * 1056 + (i0 + u) * 33 + j0];
            double xv[18];
            #pragma unroll
            for (int k = 0; k < 18; ++k) xv[k] = (double)xr[k];
            if (u < 5) {
                #pragma unroll
                for (int tt = 0; tt < 5; ++tt) wr[tt] = wp[u * 5 + tt];
                #pragma unroll
                for (int j = 0; j < 14; ++j)
                    a0[j] = fma(xv[j], wr[0], fma(xv[j+1], wr[1], fma(xv[j+2], wr[2],
                            fma(xv[j+3], wr[3], fma(xv[j+4], wr[4], a0[j])))));
            }
            if (u >= 1) {
                #pragma unroll
                for (int j = 0; j < 14; ++j)
                    a1[j] = fma(xv[j], wq[0], fma(xv[j+1], wq[1], fma(xv[j+2], wq[2],
                            fma(xv[j+3], wq[3], fma(xv[j+4], wq[4], a1[j])))));
            }
            #pragma unroll
            for (int tt = 0; tt < 5; ++tt) wq[tt] = wr[tt];   // SSA rotate
        }
        // epilogue: fq (needed for stats) + stats + 2x2 pool of the fq'd
        // values (max if g1[co]>=0 else min; monotone chain) -> 7 vals.
        double q0[14], q1[14];
        double s = 0.0, s2 = 0.0;
        #pragma unroll
        for (int j = 0; j < 14; ++j) {
            q0[j] = fq_d(a0[j]); q1[j] = fq_d(a1[j]);
            s += q0[j] + q1[j]; s2 += q0[j] * q0[j] + q1[j] * q1[j];
        }
        bool useMax = (sg1[co] >= 0.0f);
        unsigned short* dst = praw + ((size_t)(b0 + img) * 6 + co) * 196 + ph * 14 + half * 7;
        #pragma unroll
        for (int jp = 0; jp < 7; ++jp) {
            double pmax = fmax(fmax(q0[2*jp], q0[2*jp+1]), fmax(q1[2*jp], q1[2*jp+1]));
            double pmin = fmin(fmin(q0[2*jp], q0[2*jp+1]), fmin(q1[2*jp], q1[2*jp+1]));
            dst[jp] = bfbits(useMax ? pmax : pmin);
        }
        atomicAdd(&sred[co][0], s);
        atomicAdd(&sred[co][1], s2);
    }
    __syncthreads();
    if (t < 12) atomicAdd(&st1[t * 32 + (blockIdx.x & 31)], ((double*)sred)[t]);
}

// ---------------- conv2 + fused BN1 staging, f64 MFMA implicit GEMM -------
// praw [B,6,14,14] -> c2 [B,100,16]. 8 images/block, 512 thr = 8 waves,
// grid 1024 (low-traffic geometry). M = 800 positions (50 exact 16-tiles),
// N = 16 co, K = 152 (150 + 2 pad).
// BN1 finalize (st1 bins) + bn/fq/relu applied inline during x staging.
// ILP-4 chains (10/10/9/9) cover f64 MFMA dep latency.
// k-mapping k = 4m + c (2-way bank-benign); soff[152] LDS offset table;
// weights f32 staged coalesced; LDS-bounce 512B stores; D-side layout
// PROBED at runtime (r13-verified).
__global__ __launch_bounds__(512) void kconv2(const unsigned short* __restrict__ praw,
        const double* __restrict__ st1, const float* __restrict__ g1,
        const float* __restrict__ be1, const float* __restrict__ qw2t,
        __hip_bfloat16* __restrict__ c2, double* __restrict__ st2) {
    __shared__ float sxf[9408];        // 8 x [6][14][14] f32 (exact grid vals)
    __shared__ float swf[2432];        // [152][16] f32 weights, k-major (exact)
    __shared__ int soff[152];          // k -> x-tile offset (tile-invariant)
    __shared__ unsigned short sep[8][256];  // per-wave 16x16 bf16 out tile
    __shared__ double sred[16][2];
    __shared__ double sbn1[6][4];      // m, rsigma, gamma, beta
    int t = threadIdx.x;
    int b0 = blockIdx.x * 8;
    // weights: pure coalesced copy (608 x float4, L2-resident)
    {
        const float4* wsrc = (const float4*)qw2t;
        float4* wdst = (float4*)swf;
        for (int i = t; i < 608; i += 512) wdst[i] = wsrc[i];
    }
    if (t < 152)
        soff[t] = (t < 150) ? (t / 25) * 196 + ((t % 25) / 5) * 14 + (t % 5) : 0;
    if (t < 32) ((double*)sred)[t] = 0.0;
    if (t < 6) {                       // inline BN1 finalize from stat bins
        double s = 0.0, s2 = 0.0;
        for (int b = 0; b < 32; ++b) { s += st1[t * 64 + b]; s2 += st1[t * 64 + 32 + b]; }
        double m = s / 6422528.0;      // 8192*784
        double v = s2 / 6422528.0 - m * m;
        sbn1[t][0] = m; sbn1[t][1] = 1.0 / sqrt(v + 1e-5);
        sbn1[t][2] = (double)g1[t]; sbn1[t][3] = (double)be1[t];
    }
    __syncthreads();
    // stage x: praw bf16 -> bn1+fq+relu -> f32 (fused BN1).
    // 4-elem groups never cross channel boundaries (196 = 4*49).
    const ushort4* srcp = (const ushort4*)(praw + (size_t)b0 * 1176);
    for (int i = t; i < 2352; i += 512) {
        ushort4 u = srcp[i];
        int ch = ((4 * i) % 1176) / 196;
        double m = sbn1[ch][0], r = sbn1[ch][1];
        double gg = sbn1[ch][2], bb = sbn1[ch][3];
        float* d = &sxf[4 * i];
        double q;
        q = fq_d((((double)bfval(u.x) - m) * r) * gg + bb); d[0] = (float)fmax(q, 0.0);
        q = fq_d((((double)bfval(u.y) - m) * r) * gg + bb); d[1] = (float)fmax(q, 0.0);
        q = fq_d((((double)bfval(u.z) - m) * r) * gg + bb); d[2] = (float)fmax(q, 0.0);
        q = fq_d((((double)bfval(u.w) - m) * r) * gg + bb); d[3] = (float)fmax(q, 0.0);
    }
    __syncthreads();

    int l = t & 63, w = t >> 6;        // lane, wave (0..7)
    int c = l >> 4, r16 = l & 15;      // k-group / {A-row,B-col} staging index

    // ---- layout probes (exact small-int arithmetic, 2 MFMAs) ----
    d4 pz = {0.0, 0.0, 0.0, 0.0};
    d4 prow = __builtin_amdgcn_mfma_f64_16x16x4f64((double)r16, 0.25, pz, 0, 0, 0);
    d4 pcol = __builtin_amdgcn_mfma_f64_16x16x4f64(1.0, 0.25 * (double)r16, pz, 0, 0, 0);
    int rowidx[4], colidx[4];
    #pragma unroll
    for (int j = 0; j < 4; ++j) { rowidx[j] = (int)prow[j]; colidx[j] = (int)pcol[j]; }

    unsigned short* myep = sep[w];
    double ls = 0.0, ls2 = 0.0;        // per-lane stats (col fixed per lane)
    int co0 = colidx[0];
    for (int tile = w; tile < 50; tile += 8) {
        int pos = tile * 16 + r16;     // A-row (staging) for this lane
        int abase = (pos / 100) * 1176 + ((pos % 100) / 10) * 14 + (pos % 10);
        d4 a0 = {0.0, 0.0, 0.0, 0.0}, a1 = {0.0, 0.0, 0.0, 0.0};
        d4 a2 = {0.0, 0.0, 0.0, 0.0}, a3 = {0.0, 0.0, 0.0, 0.0};
        #pragma unroll
        for (int s = 0; s < 10; ++s) {
            int k0 = 4 * s + c;                 // chain 0: m in [0,10)
            int k1 = 4 * (s + 10) + c;          // chain 1: m in [10,20)
            double x0 = (double)sxf[abase + soff[k0]];
            double w0 = (double)swf[k0 * 16 + r16];
            a0 = __builtin_amdgcn_mfma_f64_16x16x4f64(x0, w0, a0, 0, 0, 0);
            double x1 = (double)sxf[abase + soff[k1]];
            double w1 = (double)swf[k1 * 16 + r16];
            a1 = __builtin_amdgcn_mfma_f64_16x16x4f64(x1, w1, a1, 0, 0, 0);
            if (s < 9) {
                int k2 = 4 * (s + 20) + c;      // chain 2: m in [20,29)
                int k3 = 4 * (s + 29) + c;      // chain 3: m in [29,38)
                double x2 = (double)sxf[abase + soff[k2]];
                double w2 = (double)swf[k2 * 16 + r16];
                a2 = __builtin_amdgcn_mfma_f64_16x16x4f64(x2, w2, a2, 0, 0, 0);
                double x3 = (double)sxf[abase + soff[k3]];
                double w3 = (double)swf[k3 * 16 + r16];
                a3 = __builtin_amdgcn_mfma_f64_16x16x4f64(x3, w3, a3, 0, 0, 0);
            }
        }
        // epilogue: fq + stats; assemble tile in LDS (probed mapping), then
        // ONE coalesced 512B wave store (c2 tile region is contiguous).
        // (a0+a1)+(a2+a3): every partial sum exact -> association-free.
        #pragma unroll
        for (int j = 0; j < 4; ++j) {
            double q = fq_d((a0[j] + a1[j]) + (a2[j] + a3[j]));
            myep[rowidx[j] * 16 + colidx[j]] = bfbits(q);
            ls += q; ls2 += q * q;
        }
        ushort4 v = *(const ushort4*)&myep[l * 4];   // wave-internal, in-order
        *(ushort4*)((unsigned short*)c2 + ((size_t)b0 * 100 + tile * 16) * 16 + l * 4) = v;
    }
    atomicAdd(&sred[co0][0], ls);
    atomicAdd(&sred[co0][1], ls2);
    __syncthreads();
    if (t < 32) atomicAdd(&st2[t * 32 + (blockIdx.x & 31)], ((double*)sred)[t]);
}

// ---------------- fused fc1+fc2+fc3 ----------------
// c2 [B,100,16] -> out [B,10]. BT=8, 256 thr, 1024 blocks.
// Stage A: inline bn2 finalize; Stage B: bn2/fq/relu/pool staging -> sx;
// Stage C: fc1 (400->120) -> s1 (LDS); Stage D: fc2 (120->84) -> s2 (LDS);
// Stage E: fc3 (84->10) -> out. One launch replaces kfc1+kfc23; a1 buffer
// and its round trip eliminated. LDS ~39.2KB.
__global__ __launch_bounds__(256) void kfc(const __hip_bfloat16* __restrict__ c2,
        const double* __restrict__ st2, const float* __restrict__ g2,
        const float* __restrict__ be2, const float* __restrict__ Wt1,
        const float* __restrict__ qfb1, const float* __restrict__ Wt2,
        const float* __restrict__ qfb2, const float* __restrict__ Wt3,
        const float* __restrict__ qfb3, float* __restrict__ out) {
    constexpr int IN = 400, BT = 8;
    __shared__ double sx[BT][IN];      // 25.6 KB
    __shared__ double s1[BT][120];     // 7.7 KB
    __shared__ double s2[BT][84];      // 5.4 KB
    __shared__ double sbn[16][4];
    int t = threadIdx.x;
    int b0 = blockIdx.x * BT;
    if (t < 16) {                       // inline bn2 finalize from stat bins
        double s = 0.0, ss = 0.0;
        for (int b = 0; b < 32; ++b) { s += st2[t * 64 + b]; ss += st2[t * 64 + 32 + b]; }
        double m = s / (819200.0);      // 8192*100
        double v = ss / (819200.0) - m * m;
        sbn[t][0] = m; sbn[t][1] = 1.0 / sqrt(v + 1e-5);
        sbn[t][2] = (double)g2[t]; sbn[t][3] = (double)be2[t];
    }
    __syncthreads();
    // Stage B: bn2 + fq + relu + 2x2 pool staging (c-fastest, coalesced)
    for (int i = t; i < BT * IN; i += 256) {
        int cc = i & 15;
        int rem = (i >> 4) % 25;
        int r = i / 400;
        int ph = rem / 5, pw = rem % 5;
        const __hip_bfloat16* src = c2 + ((size_t)(b0 + r) * 100 + 20 * ph + 2 * pw) * 16 + cc;
        double m = sbn[cc][0], rr = sbn[cc][1], gg = sbn[cc][2], bb = sbn[cc][3];
        float f0 = __bfloat162float(src[0]),   f1 = __bfloat162float(src[16]);
        float f2 = __bfloat162float(src[160]), f3 = __bfloat162float(src[176]);
        bool useMax = (rr * gg) >= 0.0;
        float v = useMax ? fmaxf(fmaxf(f0, f1), fmaxf(f2, f3))
                         : fminf(fminf(f0, f1), fminf(f2, f3));
        double q = fq_d((((double)v - m) * rr) * gg + bb);
        sx[r][cc * 25 + rem] = fmax(q, 0.0);
    }
    __syncthreads();
    {   // Stage C: fc1 -> s1.  2 groups x 4 rows x 128 output lanes.
        int o = t % 128, g = t / 128;
        double acc[4];
        double bias = (o < 120) ? (double)qfb1[o] : 0.0;
        #pragma unroll
        for (int r = 0; r < 4; ++r) acc[r] = bias;
        #pragma unroll 4
        for (int k = 0; k < IN; ++k) {
            double w = (double)Wt1[k * 128 + o];   // coalesced, L2-resident
            #pragma unroll
            for (int r = 0; r < 4; ++r)
                acc[r] = fma(sx[g * 4 + r][k], w, acc[r]);
        }
        if (o < 120) {
            #pragma unroll
            for (int r = 0; r < 4; ++r) {
                double q = fq_d(acc[r]);
                s1[g * 4 + r][o] = fmax(q, 0.0);
            }
        }
    }
    __syncthreads();
    {   // Stage D: fc2 -> s2.  2 groups x 4 rows x 128 output lanes.
        int o = t % 128, g = t / 128;
        double acc[4];
        double bias = (o < 84) ? (double)qfb2[o] : 0.0;
        #pragma unroll
        for (int r = 0; r < 4; ++r) acc[r] = bias;
        #pragma unroll 4
        for (int k = 0; k < 120; ++k) {
            double w = (double)Wt2[k * 128 + o];
            #pragma unroll
            for (int r = 0; r < 4; ++r)
                acc[r] = fma(s1[g * 4 + r][k], w, acc[r]);
        }
        if (o < 84) {
            #pragma unroll
            for (int r = 0; r < 4; ++r) {
                double q = fq_d(acc[r]);
                s2[g * 4 + r][o] = fmax(q, 0.0);
            }
        }
    }
    __syncthreads();
    {   // Stage E: fc3 -> out.  8 rows x 16 lanes (10 used), 128 threads.
        int o = t % 16, g = t / 16;
        if (g < BT) {
            double acc = (o < 10) ? (double)qfb3[o] : 0.0;
            #pragma unroll 4
            for (int k = 0; k < 84; ++k)
                acc = fma(s2[g][k], (double)Wt3[k * 16 + o], acc);
            if (o < 10)
                out[(size_t)(b0 + g) * 10 + o] = (float)fq_d(acc);
        }
    }
}

// ---------------------------------------------------------------------------
extern "C" void kernel_launch(void* const* d_in, const int* in_sizes, int n_in,
                              void* d_out, int out_size, void* d_ws, size_t ws_size,
                              hipStream_t stream) {
    const float* x   = (const float*)d_in[0];
    const float* w1  = (const float*)d_in[1];
    const float* g1  = (const float*)d_in[2];
    const float* be1 = (const float*)d_in[3];
    const float* w2  = (const float*)d_in[4];
    const float* g2  = (const float*)d_in[5];
    const float* be2 = (const float*)d_in[6];
    const float* fw1 = (const float*)d_in[7];
    const float* fb1 = (const float*)d_in[8];
    const float* fw2 = (const float*)d_in[9];
    const float* fb2 = (const float*)d_in[10];
    const float* fw3 = (const float*)d_in[11];
    const float* fb3 = (const float*)d_in[12];

    char* ws = (char*)d_ws;
    double* stats1 = (double*)(ws + 0);      // [6][2][32] dbl
    double* stats2 = (double*)(ws + 3072);   // [16][2][32] dbl (ends 11264)
    float* qw1  = (float*)(ws + 12288);
    float* qw2t = (float*)(ws + 13312);      // [152][16] f32, ends 23040
    float* qfb1 = (float*)(ws + 23040);
    float* qfb2 = (float*)(ws + 23552);
    float* qfb3 = (float*)(ws + 24064);
    float* Wt1  = (float*)(ws + 24576);      // 400*128
    float* Wt2  = (float*)(ws + 229376);     // 120*128
    float* Wt3  = (float*)(ws + 290816);     // 84*16
    unsigned short* praw = (unsigned short*)(ws + 303104);        // [B,6,14,14] 19.3 MB
    __hip_bfloat16* c2 = (__hip_bfloat16*)(ws + 19570688);        // [B,100,16] 26.2 MB

    hipMemsetAsync(ws, 0, 11264, stream);

    kprep<<<(PREP_TOTAL + 255) / 256, 256, 0, stream>>>(
        w1, w2, fb1, fb2, fb3, fw1, fw2, fw3,
        qw1, qw2t, qfb1, qfb2, qfb3, Wt1, Wt2, Wt3);

    // conv1 + fq + stats + inline pool -> praw (co-major task order)
    kconv1<<<(BATCH + 2) / 3, 512, 0, stream>>>(x, qw1, g1, praw, BATCH, stats1);
    // conv2 (fused BN1 finalize + bn/fq/relu staging; ILP-4 MFMA) -> c2
    kconv2<<<BATCH / 8, 512, 0, stream>>>(praw, stats1, g1, be1, qw2t, c2, stats2);
    // fused fc1+fc2+fc3 -> d_out [B,10] float
    kfc<<<BATCH / 8, 256, 0, stream>>>(c2, stats2, g2, be2, Wt1, qfb1,
                                       Wt2, qfb2, Wt3, qfb3, (float*)d_out);
}